// Round 1
// baseline (4685.780 us; speedup 1.0000x reference)
//
#include <hip/hip_runtime.h>

#define NN 100000
#define NE 1600000
#define NG 128
#define DIM 128
#define OUTD 64
#define NL 4

// ---------------------------------------------------------------------------
// Per-graph sum pooling. graph_ids are sorted, so each block walks a
// contiguous node range keeping a running per-feature sum, flushing with one
// atomic per (graph boundary, feature). 128 threads = one feature each.
__global__ void pool_nodes(const float* __restrict__ h, const int* __restrict__ gid,
                           float* __restrict__ pg) {
    const int f = threadIdx.x;
    int start = blockIdx.x * 512;
    int end = start + 512;
    if (end > NN) end = NN;
    int cur = gid[start];
    float acc = 0.f;
    for (int i = start; i < end; ++i) {
        int g = gid[i];
        if (g != cur) {
            unsafeAtomicAdd(&pg[cur * DIM + f], acc);
            acc = 0.f;
            cur = g;
        }
        acc += h[(size_t)i * DIM + f];
    }
    unsafeAtomicAdd(&pg[cur * DIM + f], acc);
}

// pooled = (1 + eps[l]) * h   (fully overwrites buffer; ws is poisoned)
__global__ void init_pooled(const float* __restrict__ h, const float* __restrict__ eps,
                            int l, float* __restrict__ out) {
    size_t i = (size_t)blockIdx.x * blockDim.x + threadIdx.x;
    if (i >= (size_t)NN * DIM / 4) return;
    const float s = 1.0f + eps[l];
    float4 v = ((const float4*)h)[i];
    v.x *= s; v.y *= s; v.z *= s; v.w *= s;
    ((float4*)out)[i] = v;
}

// agg[dst] += h[src] over all edges. 512 threads = 4 edges, feature = lane.
__global__ void edge_scatter(const float* __restrict__ h, const int* __restrict__ src,
                             const int* __restrict__ dst, float* __restrict__ pooled) {
    int e = blockIdx.x * 4 + (threadIdx.x >> 7);
    int f = threadIdx.x & (DIM - 1);
    if (e < NE) {
        int s = src[e], d = dst[e];
        unsafeAtomicAdd(&pooled[(size_t)d * DIM + f], h[(size_t)s * DIM + f]);
    }
}

// Y[100000x128] = transform(X) @ W[128x128] + bias, where transform is the
// folded BN+ReLU of the PREVIOUS stage: x' = relu(ta[k]*x + tc[k]) (nullable).
// Block: 64 rows x 64 cols (blockIdx.y = column half). LDS: W-half 32KB +
// X-tile 32KB (XOR-swizzled so the 4-row b32 reads hit 4 distinct banks).
__global__ __launch_bounds__(256, 2)
void gemm128(const float* __restrict__ X, const float* __restrict__ W,
             const float* __restrict__ bias,
             const float* __restrict__ ta, const float* __restrict__ tc,
             float* __restrict__ Y) {
    __shared__ float Ws[DIM * 64];
    __shared__ float Xs[64 * DIM];
    const int t = threadIdx.x;
    const int row0 = blockIdx.x * 64;
    const int ch = blockIdx.y;

#pragma unroll
    for (int i = 0; i < 8; ++i) {
        int idx = (t + i * 256) * 4;       // 0..8191 floats of the W half
        int k = idx >> 6, c = idx & 63;
        *(float4*)&Ws[k * 64 + c] = *(const float4*)(W + k * DIM + ch * 64 + c);
    }
#pragma unroll
    for (int i = 0; i < 8; ++i) {
        int idx = (t + i * 256) * 4;       // 64x128 floats of the X tile
        int r = idx >> 7, k = idx & 127;
        int gr = row0 + r;
        float4 v = make_float4(0.f, 0.f, 0.f, 0.f);
        if (gr < NN) v = *(const float4*)(X + (size_t)gr * DIM + k);
        if (ta != nullptr) {
            v.x = fmaxf(fmaf(v.x, ta[k],     tc[k]),     0.f);
            v.y = fmaxf(fmaf(v.y, ta[k + 1], tc[k + 1]), 0.f);
            v.z = fmaxf(fmaf(v.z, ta[k + 2], tc[k + 2]), 0.f);
            v.w = fmaxf(fmaf(v.w, ta[k + 3], tc[k + 3]), 0.f);
        }
        int sw = ((r >> 2) & 7) << 2;      // bank swizzle, keeps float4 alignment
        *(float4*)&Xs[r * DIM + (k ^ sw)] = v;
    }
    __syncthreads();

    const int cg = t & 15, rg = t >> 4;
    const int c0 = cg * 4, r0 = rg * 4;
    const int sw = (rg & 7) << 2;
    float acc[4][4] = {};
#pragma unroll 8
    for (int k = 0; k < DIM; ++k) {
        const float4 w = *(const float4*)&Ws[k * 64 + c0];
        const int kc = k ^ sw;
        float x0 = Xs[(r0 + 0) * DIM + kc];
        float x1 = Xs[(r0 + 1) * DIM + kc];
        float x2 = Xs[(r0 + 2) * DIM + kc];
        float x3 = Xs[(r0 + 3) * DIM + kc];
        acc[0][0] = fmaf(x0, w.x, acc[0][0]); acc[0][1] = fmaf(x0, w.y, acc[0][1]);
        acc[0][2] = fmaf(x0, w.z, acc[0][2]); acc[0][3] = fmaf(x0, w.w, acc[0][3]);
        acc[1][0] = fmaf(x1, w.x, acc[1][0]); acc[1][1] = fmaf(x1, w.y, acc[1][1]);
        acc[1][2] = fmaf(x1, w.z, acc[1][2]); acc[1][3] = fmaf(x1, w.w, acc[1][3]);
        acc[2][0] = fmaf(x2, w.x, acc[2][0]); acc[2][1] = fmaf(x2, w.y, acc[2][1]);
        acc[2][2] = fmaf(x2, w.z, acc[2][2]); acc[2][3] = fmaf(x2, w.w, acc[2][3]);
        acc[3][0] = fmaf(x3, w.x, acc[3][0]); acc[3][1] = fmaf(x3, w.y, acc[3][1]);
        acc[3][2] = fmaf(x3, w.z, acc[3][2]); acc[3][3] = fmaf(x3, w.w, acc[3][3]);
    }

    const int gc = ch * 64 + c0;
    const float4 bb = *(const float4*)(bias + gc);
#pragma unroll
    for (int i = 0; i < 4; ++i) {
        int gr = row0 + r0 + i;
        if (gr < NN) {
            float4 o;
            o.x = acc[i][0] + bb.x; o.y = acc[i][1] + bb.y;
            o.z = acc[i][2] + bb.z; o.w = acc[i][3] + bb.w;
            *(float4*)(Y + (size_t)gr * DIM + gc) = o;
        }
    }
}

// Per-column sum and sum-of-squares over the 100000-row matrix.
__global__ void col_stats(const float* __restrict__ Y, float* __restrict__ sums,
                          float* __restrict__ sqs) {
    __shared__ float s1[256], s2[256];
    const int f = threadIdx.x & 127, hh = threadIdx.x >> 7;
    int start = blockIdx.x * 256, end = start + 256;
    if (end > NN) end = NN;
    float a = 0.f, b = 0.f;
    for (int r = start + hh; r < end; r += 2) {
        float v = Y[(size_t)r * DIM + f];
        a += v;
        b = fmaf(v, v, b);
    }
    s1[threadIdx.x] = a; s2[threadIdx.x] = b;
    __syncthreads();
    if (threadIdx.x < 128) {
        unsafeAtomicAdd(&sums[f], s1[threadIdx.x] + s1[threadIdx.x + 128]);
        unsafeAtomicAdd(&sqs[f], s2[threadIdx.x] + s2[threadIdx.x + 128]);
    }
}

// Fold BN(train) + affine into x' = a*x + c per feature.
__global__ void bn_finalize(const float* __restrict__ sums, const float* __restrict__ sqs,
                            const float* __restrict__ gamma, const float* __restrict__ beta,
                            int l, float* __restrict__ ta, float* __restrict__ tc) {
    int f = threadIdx.x;
    float mu = sums[f] * (1.0f / NN);
    float var = fmaf(-mu, mu, sqs[f] * (1.0f / NN));
    float rstd = rsqrtf(var + 1e-5f);
    float a = gamma[l * DIM + f] * rstd;
    ta[f] = a;
    tc[f] = fmaf(-mu, a, beta[l * DIM + f]);
}

// h = relu(a*z + c) elementwise (materialize next layer's node features).
__global__ void bn_relu_apply(const float* __restrict__ Z, const float* __restrict__ ta,
                              const float* __restrict__ tc, float* __restrict__ H) {
    size_t i = (size_t)blockIdx.x * blockDim.x + threadIdx.x;
    if (i >= (size_t)NN * DIM / 4) return;
    int k = (int)((i * 4) & (DIM - 1));
    float4 v = ((const float4*)Z)[i];
    v.x = fmaxf(fmaf(v.x, ta[k],     tc[k]),     0.f);
    v.y = fmaxf(fmaf(v.y, ta[k + 1], tc[k + 1]), 0.f);
    v.z = fmaxf(fmaf(v.z, ta[k + 2], tc[k + 2]), 0.f);
    v.w = fmaxf(fmaf(v.w, ta[k + 3], tc[k + 3]), 0.f);
    ((float4*)H)[i] = v;
}

// score[g][o] = sum_l ( pg[l][g] . predW[l][:,o] + predb[l][o] )
__global__ void final_score(const float* __restrict__ pg, const float* __restrict__ predW,
                            const float* __restrict__ predb, float* __restrict__ out) {
    int g = blockIdx.x;
    int o = threadIdx.x;
    float acc = 0.f;
    for (int l = 0; l <= NL; ++l) {
        acc += predb[l * OUTD + o];
        const float* pgr = pg + ((size_t)l * NG + g) * DIM;
        const float* w = predW + (size_t)l * DIM * OUTD;
#pragma unroll 8
        for (int k = 0; k < DIM; ++k)
            acc = fmaf(pgr[k], w[k * OUTD + o], acc);
    }
    out[g * OUTD + o] = acc;
}

extern "C" void kernel_launch(void* const* d_in, const int* in_sizes, int n_in,
                              void* d_out, int out_size, void* d_ws, size_t ws_size,
                              hipStream_t stream) {
    const float* x     = (const float*)d_in[0];
    const int*   esrc  = (const int*)d_in[1];
    const int*   edst  = (const int*)d_in[2];
    const int*   gid   = (const int*)d_in[3];
    const float* eps   = (const float*)d_in[4];
    const float* W1    = (const float*)d_in[5];
    const float* b1    = (const float*)d_in[6];
    const float* g1    = (const float*)d_in[7];
    const float* be1   = (const float*)d_in[8];
    const float* W2    = (const float*)d_in[9];
    const float* b2    = (const float*)d_in[10];
    const float* g2    = (const float*)d_in[11];
    const float* be2   = (const float*)d_in[12];
    const float* predW = (const float*)d_in[13];
    const float* predb = (const float*)d_in[14];
    float* out = (float*)d_out;

    // ws layout: 3 node-feature buffers + pooled-per-graph + BN scratch (~154MB)
    float* A    = (float*)d_ws;
    float* B    = A + (size_t)NN * DIM;
    float* C    = B + (size_t)NN * DIM;
    float* PG   = C + (size_t)NN * DIM;
    float* SUMS = PG + 5 * NG * DIM;
    float* SQS  = SUMS + DIM;
    float* TA   = SQS + DIM;
    float* TC   = TA + DIM;

    hipMemsetAsync(PG, 0, 5 * NG * DIM * sizeof(float), stream);

    const int poolBlocks = (NN + 511) / 512;
    const int ewBlocks   = ((NN * DIM / 4) + 255) / 256;
    const int statBlocks = (NN + 255) / 256;
    dim3 gemmGrid((NN + 63) / 64, 2);

    const float* h = x;
    for (int l = 0; l < NL; ++l) {
        pool_nodes<<<poolBlocks, 128, 0, stream>>>(h, gid, PG + l * NG * DIM);
        init_pooled<<<ewBlocks, 256, 0, stream>>>(h, eps, l, B);
        edge_scatter<<<(NE + 3) / 4, 512, 0, stream>>>(h, esrc, edst, B);
        gemm128<<<gemmGrid, 256, 0, stream>>>(B, W1 + l * DIM * DIM, b1 + l * DIM,
                                              nullptr, nullptr, C);
        hipMemsetAsync(SUMS, 0, 2 * DIM * sizeof(float), stream);
        col_stats<<<statBlocks, 256, 0, stream>>>(C, SUMS, SQS);
        bn_finalize<<<1, DIM, 0, stream>>>(SUMS, SQS, g1, be1, l, TA, TC);
        gemm128<<<gemmGrid, 256, 0, stream>>>(C, W2 + l * DIM * DIM, b2 + l * DIM,
                                              TA, TC, B);
        hipMemsetAsync(SUMS, 0, 2 * DIM * sizeof(float), stream);
        col_stats<<<statBlocks, 256, 0, stream>>>(B, SUMS, SQS);
        bn_finalize<<<1, DIM, 0, stream>>>(SUMS, SQS, g2, be2, l, TA, TC);
        bn_relu_apply<<<ewBlocks, 256, 0, stream>>>(B, TA, TC, A);
        h = A;
    }
    pool_nodes<<<poolBlocks, 128, 0, stream>>>(h, gid, PG + NL * NG * DIM);
    final_score<<<NG, OUTD, 0, stream>>>(PG, predW, predb, out);
}

// Round 2
// 3181.216 us; speedup vs baseline: 1.4730x; 1.4730x over previous
//
#include <hip/hip_runtime.h>

#define NN 100000
#define NE 1600000
#define NG 128
#define DIM 128
#define OUTD 64
#define NL 4
#define SCAN_B 1024
#define NB ((NN + SCAN_B - 1) / SCAN_B)   // 98 scan blocks

// ---------------------------------------------------------------------------
// CSR build (edge list is layer-invariant: build once per call, use 4x)
__global__ void hist(const int* __restrict__ edst, int* __restrict__ deg) {
    int e = blockIdx.x * 256 + threadIdx.x;
    if (e < NE) atomicAdd(&deg[edst[e]], 1);
}

__global__ void scan_local(const int* __restrict__ deg, int* __restrict__ loc,
                           int* __restrict__ bsums) {
    __shared__ int s[256];
    int base = blockIdx.x * SCAN_B + threadIdx.x * 4;
    int d0 = 0, d1 = 0, d2 = 0, d3 = 0;
    if (base + 0 < NN) d0 = deg[base + 0];
    if (base + 1 < NN) d1 = deg[base + 1];
    if (base + 2 < NN) d2 = deg[base + 2];
    if (base + 3 < NN) d3 = deg[base + 3];
    int t4 = d0 + d1 + d2 + d3;
    s[threadIdx.x] = t4;
    __syncthreads();
    for (int off = 1; off < 256; off <<= 1) {
        int v = (threadIdx.x >= off) ? s[threadIdx.x - off] : 0;
        __syncthreads();
        s[threadIdx.x] += v;
        __syncthreads();
    }
    int excl = s[threadIdx.x] - t4;
    if (base + 0 < NN) loc[base + 0] = excl;
    if (base + 1 < NN) loc[base + 1] = excl + d0;
    if (base + 2 < NN) loc[base + 2] = excl + d0 + d1;
    if (base + 3 < NN) loc[base + 3] = excl + d0 + d1 + d2;
    if (threadIdx.x == 255) bsums[blockIdx.x] = s[255];
}

__global__ void scan_sums(int* __restrict__ bsums) {
    __shared__ int s[128];
    int v = (threadIdx.x < NB) ? bsums[threadIdx.x] : 0;
    s[threadIdx.x] = v;
    __syncthreads();
    for (int off = 1; off < 128; off <<= 1) {
        int u = (threadIdx.x >= off) ? s[threadIdx.x - off] : 0;
        __syncthreads();
        s[threadIdx.x] += u;
        __syncthreads();
    }
    if (threadIdx.x < NB) bsums[threadIdx.x] = s[threadIdx.x] - v;  // exclusive
}

__global__ void scan_add(const int* __restrict__ loc, const int* __restrict__ bsums,
                         int* __restrict__ offs, int* __restrict__ cur) {
    int i = blockIdx.x * 256 + threadIdx.x;
    if (i < NN) {
        int o = loc[i] + bsums[i >> 10];
        offs[i] = o;
        cur[i] = o;
    }
}

__global__ void scatter_edges(const int* __restrict__ esrc, const int* __restrict__ edst,
                              int* __restrict__ cur, int* __restrict__ perm) {
    int e = blockIdx.x * 256 + threadIdx.x;
    if (e < NE) {
        int pos = atomicAdd(&cur[edst[e]], 1);
        perm[pos] = esrc[e];
    }
}

// ---------------------------------------------------------------------------
// Pull-style aggregation: out[n] = (1+eps)*T(h[n]) + sum_{src in N(n)} T(h[src])
// where T = folded BN2+ReLU of previous layer (nullable). No float atomics.
// 256 threads = 2 nodes x 128 features.
__global__ void csr_agg(const float* __restrict__ h, const int* __restrict__ offs,
                        const int* __restrict__ perm, const float* __restrict__ eps, int l,
                        const float* __restrict__ ta, const float* __restrict__ tc,
                        float* __restrict__ out) {
    int n = blockIdx.x * 2 + (threadIdx.x >> 7);
    int f = threadIdx.x & 127;
    if (n >= NN) return;
    int start = offs[n];
    int end = (n == NN - 1) ? NE : offs[n + 1];
    const bool tr = (ta != nullptr);
    float a = 1.f, c = 0.f;
    if (tr) { a = ta[f]; c = tc[f]; }
    float v = h[(size_t)n * DIM + f];
    if (tr) v = fmaxf(fmaf(v, a, c), 0.f);
    float acc = (1.0f + eps[l]) * v;
    for (int j = start; j < end; ++j) {
        float u = h[(size_t)perm[j] * DIM + f];
        if (tr) u = fmaxf(fmaf(u, a, c), 0.f);
        acc += u;
    }
    out[(size_t)n * DIM + f] = acc;
}

// ---------------------------------------------------------------------------
// Y[100000x128] = T(X) @ W[128x128] + bias, T = folded inner BN+ReLU (nullable).
// Block = 64 rows x 128 cols (two 64-col halves sharing one X-tile load).
// Row-block-local read/write -> safe to run IN PLACE (Y == X).
// Fused epilogue: per-column sum / sum-of-squares into stat[0:128]/stat[128:256].
__global__ __launch_bounds__(256, 2)
void gemm128x2(const float* __restrict__ X, const float* __restrict__ W,
               const float* __restrict__ bias,
               const float* __restrict__ ta, const float* __restrict__ tc,
               float* __restrict__ Y, float* __restrict__ stat) {
    __shared__ float Ws[DIM * 64];
    __shared__ float Xs[64 * DIM];
    const int t = threadIdx.x;
    const int row0 = blockIdx.x * 64;

    // X tile (64 x 128) -> LDS, once, with optional transform, XOR-swizzled
#pragma unroll
    for (int i = 0; i < 8; ++i) {
        int idx = (t + i * 256) * 4;
        int r = idx >> 7, k = idx & 127;
        int gr = row0 + r;
        float4 v = make_float4(0.f, 0.f, 0.f, 0.f);
        if (gr < NN) v = *(const float4*)(X + (size_t)gr * DIM + k);
        if (ta != nullptr) {
            v.x = fmaxf(fmaf(v.x, ta[k],     tc[k]),     0.f);
            v.y = fmaxf(fmaf(v.y, ta[k + 1], tc[k + 1]), 0.f);
            v.z = fmaxf(fmaf(v.z, ta[k + 2], tc[k + 2]), 0.f);
            v.w = fmaxf(fmaf(v.w, ta[k + 3], tc[k + 3]), 0.f);
        }
        int sw = ((r >> 2) & 7) << 2;
        *(float4*)&Xs[r * DIM + (k ^ sw)] = v;
    }

    const int cg = t & 15, rg = t >> 4;
    const int c0 = cg * 4, r0 = rg * 4;
    const int sw = (rg & 7) << 2;
    float accA[4][4] = {}, accB[4][4] = {};

    for (int ch = 0; ch < 2; ++ch) {
        __syncthreads();   // ch=0: Xs visible; ch=1: prev k-loop done before Ws overwrite
#pragma unroll
        for (int i = 0; i < 8; ++i) {
            int idx = (t + i * 256) * 4;
            int k = idx >> 6, cc = idx & 63;
            *(float4*)&Ws[k * 64 + cc] = *(const float4*)(W + k * DIM + ch * 64 + cc);
        }
        __syncthreads();
        float (*acc)[4] = ch ? accB : accA;
#pragma unroll 8
        for (int k = 0; k < DIM; ++k) {
            const float4 w = *(const float4*)&Ws[k * 64 + c0];
            const int kc = k ^ sw;
            float x0 = Xs[(r0 + 0) * DIM + kc];
            float x1 = Xs[(r0 + 1) * DIM + kc];
            float x2 = Xs[(r0 + 2) * DIM + kc];
            float x3 = Xs[(r0 + 3) * DIM + kc];
            acc[0][0] = fmaf(x0, w.x, acc[0][0]); acc[0][1] = fmaf(x0, w.y, acc[0][1]);
            acc[0][2] = fmaf(x0, w.z, acc[0][2]); acc[0][3] = fmaf(x0, w.w, acc[0][3]);
            acc[1][0] = fmaf(x1, w.x, acc[1][0]); acc[1][1] = fmaf(x1, w.y, acc[1][1]);
            acc[1][2] = fmaf(x1, w.z, acc[1][2]); acc[1][3] = fmaf(x1, w.w, acc[1][3]);
            acc[2][0] = fmaf(x2, w.x, acc[2][0]); acc[2][1] = fmaf(x2, w.y, acc[2][1]);
            acc[2][2] = fmaf(x2, w.z, acc[2][2]); acc[2][3] = fmaf(x2, w.w, acc[2][3]);
            acc[3][0] = fmaf(x3, w.x, acc[3][0]); acc[3][1] = fmaf(x3, w.y, acc[3][1]);
            acc[3][2] = fmaf(x3, w.z, acc[3][2]); acc[3][3] = fmaf(x3, w.w, acc[3][3]);
        }
    }

    // epilogue: bias, store, per-column partial stats
    const float4 bA = *(const float4*)(bias + c0);
    const float4 bB = *(const float4*)(bias + 64 + c0);
    float s[8] = {}, q[8] = {};
#pragma unroll
    for (int i = 0; i < 4; ++i) {
        int gr = row0 + r0 + i;
        if (gr < NN) {
            float4 oA, oB;
            oA.x = accA[i][0] + bA.x; oA.y = accA[i][1] + bA.y;
            oA.z = accA[i][2] + bA.z; oA.w = accA[i][3] + bA.w;
            oB.x = accB[i][0] + bB.x; oB.y = accB[i][1] + bB.y;
            oB.z = accB[i][2] + bB.z; oB.w = accB[i][3] + bB.w;
            *(float4*)(Y + (size_t)gr * DIM + c0)      = oA;
            *(float4*)(Y + (size_t)gr * DIM + 64 + c0) = oB;
            s[0] += oA.x; s[1] += oA.y; s[2] += oA.z; s[3] += oA.w;
            s[4] += oB.x; s[5] += oB.y; s[6] += oB.z; s[7] += oB.w;
            q[0] = fmaf(oA.x, oA.x, q[0]); q[1] = fmaf(oA.y, oA.y, q[1]);
            q[2] = fmaf(oA.z, oA.z, q[2]); q[3] = fmaf(oA.w, oA.w, q[3]);
            q[4] = fmaf(oB.x, oB.x, q[4]); q[5] = fmaf(oB.y, oB.y, q[5]);
            q[6] = fmaf(oB.z, oB.z, q[6]); q[7] = fmaf(oB.w, oB.w, q[7]);
        }
    }
    __syncthreads();                     // done reading Xs -> reuse for reduction
    float* red = Xs;                     // [16 rg][16 cg][16 vals]
#pragma unroll
    for (int j = 0; j < 8; ++j) {
        red[(rg * 16 + cg) * 16 + j]     = s[j];
        red[(rg * 16 + cg) * 16 + 8 + j] = q[j];
    }
    __syncthreads();
    if (t < 16) {
        float tot[16] = {};
        for (int r = 0; r < 16; ++r)
#pragma unroll
            for (int j = 0; j < 16; ++j) tot[j] += red[(r * 16 + t) * 16 + j];
        // layout of tot: [sumA4, sqA4... ] j<8 = s/q interleave per above store
#pragma unroll
        for (int j = 0; j < 4; ++j) {
            unsafeAtomicAdd(&stat[t * 4 + j],            tot[j]);        // sum colA
            unsafeAtomicAdd(&stat[64 + t * 4 + j],       tot[4 + j]);    // sum colB
            unsafeAtomicAdd(&stat[DIM + t * 4 + j],      tot[8 + j]);    // sq colA
            unsafeAtomicAdd(&stat[DIM + 64 + t * 4 + j], tot[12 + j]);   // sq colB
        }
    }
}

// Fold BN(train) + affine into x' = a*x + c per feature.
__global__ void bn_finalize(const float* __restrict__ stat,
                            const float* __restrict__ gamma, const float* __restrict__ beta,
                            int l, float* __restrict__ ta, float* __restrict__ tc) {
    int f = threadIdx.x;
    float mu = stat[f] * (1.0f / NN);
    float var = fmaf(-mu, mu, stat[DIM + f] * (1.0f / NN));
    float rstd = rsqrtf(var + 1e-5f);
    float a = gamma[l * DIM + f] * rstd;
    ta[f] = a;
    tc[f] = fmaf(-mu, a, beta[l * DIM + f]);
}

// Per-graph sum pooling with optional folded transform (sorted graph_ids).
__global__ void pool_nodes(const float* __restrict__ h, const int* __restrict__ gid,
                           const float* __restrict__ ta, const float* __restrict__ tc,
                           float* __restrict__ pg) {
    const int f = threadIdx.x;
    int start = blockIdx.x * 128;
    int end = start + 128;
    if (end > NN) end = NN;
    const bool tr = (ta != nullptr);
    float a = 1.f, c = 0.f;
    if (tr) { a = ta[f]; c = tc[f]; }
    int cur = gid[start];
    float acc = 0.f;
    for (int i = start; i < end; ++i) {
        int g = gid[i];
        if (g != cur) {
            unsafeAtomicAdd(&pg[cur * DIM + f], acc);
            acc = 0.f;
            cur = g;
        }
        float v = h[(size_t)i * DIM + f];
        if (tr) v = fmaxf(fmaf(v, a, c), 0.f);
        acc += v;
    }
    unsafeAtomicAdd(&pg[cur * DIM + f], acc);
}

__global__ void final_score(const float* __restrict__ pg, const float* __restrict__ predW,
                            const float* __restrict__ predb, float* __restrict__ out) {
    int g = blockIdx.x;
    int o = threadIdx.x;
    float acc = 0.f;
    for (int l = 0; l <= NL; ++l) {
        acc += predb[l * OUTD + o];
        const float* pgr = pg + ((size_t)l * NG + g) * DIM;
        const float* w = predW + (size_t)l * DIM * OUTD;
#pragma unroll 8
        for (int k = 0; k < DIM; ++k)
            acc = fmaf(pgr[k], w[k * OUTD + o], acc);
    }
    out[g * OUTD + o] = acc;
}

extern "C" void kernel_launch(void* const* d_in, const int* in_sizes, int n_in,
                              void* d_out, int out_size, void* d_ws, size_t ws_size,
                              hipStream_t stream) {
    const float* x     = (const float*)d_in[0];
    const int*   esrc  = (const int*)d_in[1];
    const int*   edst  = (const int*)d_in[2];
    const int*   gid   = (const int*)d_in[3];
    const float* eps   = (const float*)d_in[4];
    const float* W1    = (const float*)d_in[5];
    const float* b1    = (const float*)d_in[6];
    const float* g1    = (const float*)d_in[7];
    const float* be1   = (const float*)d_in[8];
    const float* W2    = (const float*)d_in[9];
    const float* b2    = (const float*)d_in[10];
    const float* g2    = (const float*)d_in[11];
    const float* be2   = (const float*)d_in[12];
    const float* predW = (const float*)d_in[13];
    const float* predb = (const float*)d_in[14];
    float* out = (float*)d_out;

    // ws layout (~111 MB): 2 node buffers + PG + stats + CSR arrays
    float* A    = (float*)d_ws;
    float* B    = A + (size_t)NN * DIM;
    float* PG   = B + (size_t)NN * DIM;
    float* STAT = PG + 5 * NG * DIM;          // 512 floats: [S1(256) | S2(256)]
    float* TA1  = STAT + 512;
    float* TC1  = TA1 + DIM;
    float* TA2  = TC1 + DIM;
    float* TC2  = TA2 + DIM;
    int* DEG  = (int*)(TC2 + DIM);
    int* LOC  = DEG + NN;
    int* OFFS = LOC + NN;
    int* CUR  = OFFS + NN;
    int* BS   = CUR + NN;
    int* PERM = BS + 128;

    hipMemsetAsync(PG, 0, 5 * NG * DIM * sizeof(float), stream);
    hipMemsetAsync(DEG, 0, NN * sizeof(int), stream);

    // ---- CSR build (once; edge list reused by all 4 layers)
    const int eBlocks = (NE + 255) / 256;
    hist<<<eBlocks, 256, 0, stream>>>(edst, DEG);
    scan_local<<<NB, 256, 0, stream>>>(DEG, LOC, BS);
    scan_sums<<<1, 128, 0, stream>>>(BS);
    scan_add<<<(NN + 255) / 256, 256, 0, stream>>>(LOC, BS, OFFS, CUR);
    scatter_edges<<<eBlocks, 256, 0, stream>>>(esrc, edst, CUR, PERM);

    const int poolBlocks = (NN + 127) / 128;
    const int aggBlocks  = (NN + 1) / 2;
    const int gemmBlocks = (NN + 63) / 64;

    const float* h = x;
    const float* ta2 = nullptr;
    const float* tc2 = nullptr;
    for (int l = 0; l < NL; ++l) {
        pool_nodes<<<poolBlocks, 128, 0, stream>>>(h, gid, ta2, tc2, PG + l * NG * DIM);
        csr_agg<<<aggBlocks, 256, 0, stream>>>(h, OFFS, PERM, eps, l, ta2, tc2, B);
        hipMemsetAsync(STAT, 0, 512 * sizeof(float), stream);
        gemm128x2<<<gemmBlocks, 256, 0, stream>>>(B, W1 + l * DIM * DIM, b1 + l * DIM,
                                                  nullptr, nullptr, B, STAT);       // in place
        bn_finalize<<<1, DIM, 0, stream>>>(STAT, g1, be1, l, TA1, TC1);
        gemm128x2<<<gemmBlocks, 256, 0, stream>>>(B, W2 + l * DIM * DIM, b2 + l * DIM,
                                                  TA1, TC1, A, STAT + 256);
        bn_finalize<<<1, DIM, 0, stream>>>(STAT + 256, g2, be2, l, TA2, TC2);
        h = A; ta2 = TA2; tc2 = TC2;
    }
    pool_nodes<<<poolBlocks, 128, 0, stream>>>(h, gid, ta2, tc2, PG + NL * NG * DIM);
    final_score<<<NG, OUTD, 0, stream>>>(PG, predW, predb, out);
}

// Round 3
// 1456.518 us; speedup vs baseline: 3.2171x; 2.1841x over previous
//
#include <hip/hip_runtime.h>

#define NN 100000
#define NE 1600000
#define NG 128
#define DIM 128
#define OUTD 64
#define NL 4
#define SCAN_B 1024
#define NB ((NN + SCAN_B - 1) / SCAN_B)   // 98 scan blocks

typedef __attribute__((ext_vector_type(8))) short bf16x8;
typedef __attribute__((ext_vector_type(4))) float floatx4;

__device__ __forceinline__ float bf_lo(unsigned u) {
    union { unsigned u; float f; } c; c.u = u << 16; return c.f;
}
__device__ __forceinline__ float bf_hi(unsigned u) {
    union { unsigned u; float f; } c; c.u = u & 0xffff0000u; return c.f;
}
__device__ __forceinline__ unsigned f2bf(float x) {   // RNE
    union { float f; unsigned u; } c; c.f = x;
    return (c.u + 0x7fffu + ((c.u >> 16) & 1u)) >> 16;
}
__device__ __forceinline__ float bfs2f(short s) {
    union { unsigned u; float f; } c; c.u = ((unsigned)(unsigned short)s) << 16; return c.f;
}

// ---------------------------------------------------------------------------
// CSR build (edge list is layer-invariant: build once per call, use 4x)
__global__ void hist(const int* __restrict__ edst, int* __restrict__ deg) {
    int e = blockIdx.x * 256 + threadIdx.x;
    if (e < NE) atomicAdd(&deg[edst[e]], 1);
}

__global__ void scan_local(const int* __restrict__ deg, int* __restrict__ loc,
                           int* __restrict__ bsums) {
    __shared__ int s[256];
    int base = blockIdx.x * SCAN_B + threadIdx.x * 4;
    int d0 = 0, d1 = 0, d2 = 0, d3 = 0;
    if (base + 0 < NN) d0 = deg[base + 0];
    if (base + 1 < NN) d1 = deg[base + 1];
    if (base + 2 < NN) d2 = deg[base + 2];
    if (base + 3 < NN) d3 = deg[base + 3];
    int t4 = d0 + d1 + d2 + d3;
    s[threadIdx.x] = t4;
    __syncthreads();
    for (int off = 1; off < 256; off <<= 1) {
        int v = (threadIdx.x >= off) ? s[threadIdx.x - off] : 0;
        __syncthreads();
        s[threadIdx.x] += v;
        __syncthreads();
    }
    int excl = s[threadIdx.x] - t4;
    if (base + 0 < NN) loc[base + 0] = excl;
    if (base + 1 < NN) loc[base + 1] = excl + d0;
    if (base + 2 < NN) loc[base + 2] = excl + d0 + d1;
    if (base + 3 < NN) loc[base + 3] = excl + d0 + d1 + d2;
    if (threadIdx.x == 255) bsums[blockIdx.x] = s[255];
}

__global__ void scan_sums(int* __restrict__ bsums) {
    __shared__ int s[128];
    int v = (threadIdx.x < NB) ? bsums[threadIdx.x] : 0;
    s[threadIdx.x] = v;
    __syncthreads();
    for (int off = 1; off < 128; off <<= 1) {
        int u = (threadIdx.x >= off) ? s[threadIdx.x - off] : 0;
        __syncthreads();
        s[threadIdx.x] += u;
        __syncthreads();
    }
    if (threadIdx.x < NB) bsums[threadIdx.x] = s[threadIdx.x] - v;  // exclusive
}

__global__ void scan_add(const int* __restrict__ loc, const int* __restrict__ bsums,
                         int* __restrict__ offs, int* __restrict__ cur) {
    int i = blockIdx.x * 256 + threadIdx.x;
    if (i < NN) {
        int o = loc[i] + bsums[i >> 10];
        offs[i] = o;
        cur[i] = o;
    }
}

__global__ void scatter_edges(const int* __restrict__ esrc, const int* __restrict__ edst,
                              int* __restrict__ cur, int* __restrict__ perm) {
    int e = blockIdx.x * 256 + threadIdx.x;
    if (e < NE) {
        int pos = atomicAdd(&cur[edst[e]], 1);
        perm[pos] = esrc[e];
    }
}

// ---------------------------------------------------------------------------
// fp32 -> bf16 convert (x once per call)
__global__ void to_bf16(const float* __restrict__ x, unsigned* __restrict__ xb) {
    size_t i = ((size_t)blockIdx.x * 256 + threadIdx.x) * 4;
    float4 v = *(const float4*)(x + i);
    uint2 o;
    o.x = f2bf(v.x) | (f2bf(v.y) << 16);
    o.y = f2bf(v.z) | (f2bf(v.w) << 16);
    *(uint2*)(xb + i / 2) = o;
}

// Build Wt[mat][n][k] bf16 from 8 fp32 weight matrices (once per call).
__global__ void build_wt(const float* __restrict__ W1, const float* __restrict__ W2,
                         unsigned short* __restrict__ Wt) {
    int b = blockIdx.x;              // 0..7: layer = b>>1, which = b&1
    const float* W = ((b & 1) ? W2 : W1) + (size_t)(b >> 1) * DIM * DIM;
    unsigned short* O = Wt + (size_t)b * DIM * DIM;
    for (int i = threadIdx.x; i < DIM * DIM; i += 256) {
        int k = i >> 7, n = i & 127;
        O[n * DIM + k] = (unsigned short)f2bf(W[i]);
    }
}

// ---------------------------------------------------------------------------
// Pull aggregation in bf16: out[n] = (1+eps)*T(h[n]) + sum_{src} T(h[src]).
// 256 threads = 4 nodes x 64 lanes; lane owns feature pair (2*lane, 2*lane+1).
// Gather addresses are wave-uniform base + lane -> fully coalesced 256B rows.
template<int TR>
__global__ void csr_agg(const unsigned* __restrict__ hq, const int* __restrict__ offs,
                        const int* __restrict__ perm, const float* __restrict__ eps, int l,
                        const float* __restrict__ ta, const float* __restrict__ tc,
                        unsigned* __restrict__ outq) {
    int node = blockIdx.x * 4 + (threadIdx.x >> 6);
    int lane = threadIdx.x & 63;
    if (node >= NN) return;
    int start = offs[node];
    int end = (node == NN - 1) ? NE : offs[node + 1];
    int f = lane * 2;
    float a0 = 0.f, c0 = 0.f, a1 = 0.f, c1 = 0.f;
    if (TR) { a0 = ta[f]; c0 = tc[f]; a1 = ta[f + 1]; c1 = tc[f + 1]; }
    unsigned v = hq[(size_t)node * 64 + lane];
    float x0 = bf_lo(v), x1 = bf_hi(v);
    if (TR) {
        x0 = fmaxf(fmaf(x0, a0, c0), 0.f);
        x1 = fmaxf(fmaf(x1, a1, c1), 0.f);
    }
    float e1 = 1.0f + eps[l];
    float acc0 = e1 * x0, acc1 = e1 * x1;
    int j = start;
    for (; j + 1 < end; j += 2) {
        int s0 = perm[j], s1 = perm[j + 1];
        unsigned u0 = hq[(size_t)s0 * 64 + lane];
        unsigned u1 = hq[(size_t)s1 * 64 + lane];
        float p0 = bf_lo(u0), p1 = bf_hi(u0), p2 = bf_lo(u1), p3 = bf_hi(u1);
        if (TR) {
            p0 = fmaxf(fmaf(p0, a0, c0), 0.f); p1 = fmaxf(fmaf(p1, a1, c1), 0.f);
            p2 = fmaxf(fmaf(p2, a0, c0), 0.f); p3 = fmaxf(fmaf(p3, a1, c1), 0.f);
        }
        acc0 += p0 + p2; acc1 += p1 + p3;
    }
    if (j < end) {
        unsigned u0 = hq[(size_t)perm[j] * 64 + lane];
        float p0 = bf_lo(u0), p1 = bf_hi(u0);
        if (TR) {
            p0 = fmaxf(fmaf(p0, a0, c0), 0.f);
            p1 = fmaxf(fmaf(p1, a1, c1), 0.f);
        }
        acc0 += p0; acc1 += p1;
    }
    outq[(size_t)node * 64 + lane] = f2bf(acc0) | (f2bf(acc1) << 16);
}

// ---------------------------------------------------------------------------
// Y[NN x 128] = T(X) @ W + bias via mfma_f32_16x16x32_bf16, no LDS staging.
// Block = 4 waves x 32 rows = 128 rows. A-frags direct from global X
// (A[m=lane&15][k=quad*8+j]); B-frags from pre-transposed Wt[n][k] (L2-hot).
// Fused epilogue: bf16 store + per-column sum/sumsq -> stat[0:128]/[128:256].
// Row-local in-place safe (each wave reads only rows it later writes).
__global__ __launch_bounds__(256, 2)
void gemm_mfma(const unsigned short* __restrict__ X, const unsigned short* __restrict__ Wt,
               const float* __restrict__ bias,
               const float* __restrict__ ta, const float* __restrict__ tc,
               unsigned short* __restrict__ Y, float* __restrict__ stat) {
    __shared__ float red[4 * 256];
    const int t = threadIdx.x;
    const int w = t >> 6, lane = t & 63;
    const int quad = lane >> 4, m = lane & 15;
    const int rowbase = blockIdx.x * 128 + w * 32;
    const bool tr = (ta != nullptr);

    bf16x8 a[2][4];
#pragma unroll
    for (int rt = 0; rt < 2; ++rt) {
        int row = rowbase + rt * 16 + m;
        if (row > NN - 1) row = NN - 1;
        const unsigned short* xr = X + (size_t)row * DIM + quad * 8;
#pragma unroll
        for (int ks = 0; ks < 4; ++ks) {
            bf16x8 v = *(const bf16x8*)(xr + ks * 32);
            if (tr) {
                int kk = ks * 32 + quad * 8;
#pragma unroll
                for (int j = 0; j < 8; ++j) {
                    float fv = bfs2f(v[j]);
                    fv = fmaxf(fmaf(fv, ta[kk + j], tc[kk + j]), 0.f);
                    v[j] = (short)f2bf(fv);
                }
            }
            a[rt][ks] = v;
        }
    }

    floatx4 acc[2][8];
#pragma unroll
    for (int rt = 0; rt < 2; ++rt)
#pragma unroll
        for (int ct = 0; ct < 8; ++ct) acc[rt][ct] = (floatx4)0.f;

#pragma unroll
    for (int ct = 0; ct < 8; ++ct) {
        const unsigned short* wr = Wt + (size_t)(ct * 16 + m) * DIM + quad * 8;
#pragma unroll
        for (int ks = 0; ks < 4; ++ks) {
            bf16x8 b = *(const bf16x8*)(wr + ks * 32);
            acc[0][ct] = __builtin_amdgcn_mfma_f32_16x16x32_bf16(a[0][ks], b, acc[0][ct], 0, 0, 0);
            acc[1][ct] = __builtin_amdgcn_mfma_f32_16x16x32_bf16(a[1][ks], b, acc[1][ct], 0, 0, 0);
        }
    }

    // epilogue: bias + bf16 store + masked column stats
#pragma unroll
    for (int ct = 0; ct < 8; ++ct) {
        int col = ct * 16 + m;
        float bv = bias[col];
        float s = 0.f, q = 0.f;
#pragma unroll
        for (int rt = 0; rt < 2; ++rt) {
#pragma unroll
            for (int r = 0; r < 4; ++r) {
                int row = rowbase + rt * 16 + quad * 4 + r;
                float val = acc[rt][ct][r] + bv;
                if (row < NN) {
                    Y[(size_t)row * DIM + col] = (unsigned short)f2bf(val);
                    s += val;
                    q = fmaf(val, val, q);
                }
            }
        }
        s += __shfl_xor(s, 16); s += __shfl_xor(s, 32);
        q += __shfl_xor(q, 16); q += __shfl_xor(q, 32);
        if (quad == 0) { red[w * 256 + col] = s; red[w * 256 + 128 + col] = q; }
    }
    __syncthreads();
    if (t < 256) {
        float tot = red[t] + red[256 + t] + red[512 + t] + red[768 + t];
        unsafeAtomicAdd(&stat[t], tot);
    }
}

// Fold BN(train) + affine into x' = a*x + c per feature.
__global__ void bn_finalize(const float* __restrict__ stat,
                            const float* __restrict__ gamma, const float* __restrict__ beta,
                            int l, float* __restrict__ ta, float* __restrict__ tc) {
    int f = threadIdx.x;
    float mu = stat[f] * (1.0f / NN);
    float var = fmaf(-mu, mu, stat[DIM + f] * (1.0f / NN));
    float rstd = rsqrtf(var + 1e-5f);
    float a = gamma[l * DIM + f] * rstd;
    ta[f] = a;
    tc[f] = fmaf(-mu, a, beta[l * DIM + f]);
}

// Per-graph sum pooling (sorted graph_ids), bf16 input, fp32 accumulation.
template<int TR>
__global__ void pool_nodes(const unsigned* __restrict__ hq, const int* __restrict__ gid,
                           const float* __restrict__ ta, const float* __restrict__ tc,
                           float* __restrict__ pg) {
    const int lane = threadIdx.x;            // 64 threads, feature pair per lane
    int start = blockIdx.x * 128;
    int end = start + 128;
    if (end > NN) end = NN;
    int f = lane * 2;
    float a0 = 0.f, c0 = 0.f, a1 = 0.f, c1 = 0.f;
    if (TR) { a0 = ta[f]; c0 = tc[f]; a1 = ta[f + 1]; c1 = tc[f + 1]; }
    int cur = gid[start];
    float acc0 = 0.f, acc1 = 0.f;
    for (int i = start; i < end; ++i) {
        int g = gid[i];
        if (g != cur) {
            unsafeAtomicAdd(&pg[cur * DIM + f], acc0);
            unsafeAtomicAdd(&pg[cur * DIM + f + 1], acc1);
            acc0 = 0.f; acc1 = 0.f;
            cur = g;
        }
        unsigned u = hq[(size_t)i * 64 + lane];
        float x0 = bf_lo(u), x1 = bf_hi(u);
        if (TR) {
            x0 = fmaxf(fmaf(x0, a0, c0), 0.f);
            x1 = fmaxf(fmaf(x1, a1, c1), 0.f);
        }
        acc0 += x0; acc1 += x1;
    }
    unsafeAtomicAdd(&pg[cur * DIM + f], acc0);
    unsafeAtomicAdd(&pg[cur * DIM + f + 1], acc1);
}

__global__ void final_score(const float* __restrict__ pg, const float* __restrict__ predW,
                            const float* __restrict__ predb, float* __restrict__ out) {
    int g = blockIdx.x;
    int o = threadIdx.x;
    float acc = 0.f;
    for (int l = 0; l <= NL; ++l) {
        acc += predb[l * OUTD + o];
        const float* pgr = pg + ((size_t)l * NG + g) * DIM;
        const float* w = predW + (size_t)l * DIM * OUTD;
#pragma unroll 8
        for (int k = 0; k < DIM; ++k)
            acc = fmaf(pgr[k], w[k * OUTD + o], acc);
    }
    out[g * OUTD + o] = acc;
}

extern "C" void kernel_launch(void* const* d_in, const int* in_sizes, int n_in,
                              void* d_out, int out_size, void* d_ws, size_t ws_size,
                              hipStream_t stream) {
    const float* x     = (const float*)d_in[0];
    const int*   esrc  = (const int*)d_in[1];
    const int*   edst  = (const int*)d_in[2];
    const int*   gid   = (const int*)d_in[3];
    const float* eps   = (const float*)d_in[4];
    const float* W1    = (const float*)d_in[5];
    const float* b1    = (const float*)d_in[6];
    const float* g1    = (const float*)d_in[7];
    const float* be1   = (const float*)d_in[8];
    const float* W2    = (const float*)d_in[9];
    const float* b2    = (const float*)d_in[10];
    const float* g2    = (const float*)d_in[11];
    const float* be2   = (const float*)d_in[12];
    const float* predW = (const float*)d_in[13];
    const float* predb = (const float*)d_in[14];
    float* out = (float*)d_out;

    // ws layout (~85 MB): 3 bf16 node buffers + Wt + PG + stats + CSR arrays
    unsigned short* XB = (unsigned short*)d_ws;
    unsigned short* A  = XB + (size_t)NN * DIM;
    unsigned short* B  = A + (size_t)NN * DIM;
    unsigned short* WT = B + (size_t)NN * DIM;
    float* PG   = (float*)(WT + 8 * DIM * DIM);
    float* STAT = PG + 5 * NG * DIM;          // 512 floats: [S1|SQ1 | S2|SQ2]
    float* TA1  = STAT + 512;
    float* TC1  = TA1 + DIM;
    float* TA2  = TC1 + DIM;
    float* TC2  = TA2 + DIM;
    int* DEG  = (int*)(TC2 + DIM);
    int* LOC  = DEG + NN;
    int* OFFS = LOC + NN;
    int* CUR  = OFFS + NN;
    int* BS   = CUR + NN;
    int* PERM = BS + 128;

    hipMemsetAsync(PG, 0, 5 * NG * DIM * sizeof(float), stream);
    hipMemsetAsync(DEG, 0, NN * sizeof(int), stream);

    // ---- one-time per call: CSR build, x->bf16, transposed bf16 weights
    const int eBlocks = (NE + 255) / 256;
    hist<<<eBlocks, 256, 0, stream>>>(edst, DEG);
    scan_local<<<NB, 256, 0, stream>>>(DEG, LOC, BS);
    scan_sums<<<1, 128, 0, stream>>>(BS);
    scan_add<<<(NN + 255) / 256, 256, 0, stream>>>(LOC, BS, OFFS, CUR);
    scatter_edges<<<eBlocks, 256, 0, stream>>>(esrc, edst, CUR, PERM);
    to_bf16<<<(NN * DIM) / 1024, 256, 0, stream>>>(x, (unsigned*)XB);
    build_wt<<<8, 256, 0, stream>>>(W1, W2, WT);

    const int poolBlocks = (NN + 127) / 128;
    const int aggBlocks  = (NN + 3) / 4;
    const int gemmBlocks = (NN + 127) / 128;

    const unsigned* h = (const unsigned*)XB;
    for (int l = 0; l < NL; ++l) {
        if (l == 0) {
            pool_nodes<0><<<poolBlocks, 64, 0, stream>>>(h, gid, nullptr, nullptr, PG);
            csr_agg<0><<<aggBlocks, 256, 0, stream>>>(h, OFFS, PERM, eps, l,
                                                      nullptr, nullptr, (unsigned*)B);
        } else {
            pool_nodes<1><<<poolBlocks, 64, 0, stream>>>(h, gid, TA2, TC2, PG + l * NG * DIM);
            csr_agg<1><<<aggBlocks, 256, 0, stream>>>(h, OFFS, PERM, eps, l,
                                                      TA2, TC2, (unsigned*)B);
        }
        hipMemsetAsync(STAT, 0, 512 * sizeof(float), stream);
        gemm_mfma<<<gemmBlocks, 256, 0, stream>>>(B, WT + (size_t)(2 * l) * DIM * DIM,
                                                  b1 + l * DIM, nullptr, nullptr, B, STAT);
        bn_finalize<<<1, DIM, 0, stream>>>(STAT, g1, be1, l, TA1, TC1);
        gemm_mfma<<<gemmBlocks, 256, 0, stream>>>(B, WT + (size_t)(2 * l + 1) * DIM * DIM,
                                                  b2 + l * DIM, TA1, TC1, A, STAT + 256);
        bn_finalize<<<1, DIM, 0, stream>>>(STAT + 256, g2, be2, l, TA2, TC2);
        h = (const unsigned*)A;
    }
    pool_nodes<1><<<poolBlocks, 64, 0, stream>>>(h, gid, TA2, TC2, PG + NL * NG * DIM);
    final_score<<<NG, OUTD, 0, stream>>>(PG, predW, predb, out);
}

// Round 4
// 1451.382 us; speedup vs baseline: 3.2285x; 1.0035x over previous
//
#include <hip/hip_runtime.h>

#define NN 100000
#define NE 1600000
#define NG 128
#define DIM 128
#define OUTD 64
#define NL 4
#define BSH 7                       // 128 nodes per bucket
#define NBK ((NN + 127) >> BSH)     // 782 buckets

typedef __attribute__((ext_vector_type(8))) short bf16x8;
typedef __attribute__((ext_vector_type(4))) float floatx4;

__device__ __forceinline__ float bf_lo(unsigned u) {
    union { unsigned u; float f; } c; c.u = u << 16; return c.f;
}
__device__ __forceinline__ float bf_hi(unsigned u) {
    union { unsigned u; float f; } c; c.u = u & 0xffff0000u; return c.f;
}
__device__ __forceinline__ unsigned f2bf(float x) {   // RNE
    union { float f; unsigned u; } c; c.f = x;
    return (c.u + 0x7fffu + ((c.u >> 16) & 1u)) >> 16;
}
__device__ __forceinline__ float bfs2f(short s) {
    union { unsigned u; float f; } c; c.u = ((unsigned)(unsigned short)s) << 16; return c.f;
}

// ---------------------------------------------------------------------------
// Bucketed CSR build. Bucket b owns nodes [b*128, b*128+128): every edge with
// dst in that range lands in bucket b, so per-bucket CSR positions are block-
// local (LDS cursors, cache-resident perm windows). No global CUR, no hist.
__global__ void bhist(const int* __restrict__ edst, int* __restrict__ bcnt) {
    __shared__ int cnt[NBK];
    for (int i = threadIdx.x; i < NBK; i += 256) cnt[i] = 0;
    __syncthreads();
    int base = blockIdx.x * 4096;
    int end = base + 4096; if (end > NE) end = NE;
    for (int e = base + threadIdx.x; e < end; e += 256)
        atomicAdd(&cnt[edst[e] >> BSH], 1);
    __syncthreads();
    for (int i = threadIdx.x; i < NBK; i += 256)
        if (cnt[i]) atomicAdd(&bcnt[i], cnt[i]);
}

__global__ void bscan(const int* __restrict__ bcnt, int* __restrict__ boff,
                      int* __restrict__ bcur) {
    __shared__ int s[1024];
    int t = threadIdx.x;
    int v = (t < NBK) ? bcnt[t] : 0;
    s[t] = v;
    __syncthreads();
    for (int off = 1; off < 1024; off <<= 1) {
        int u = (t >= off) ? s[t - off] : 0;
        __syncthreads();
        s[t] += u;
        __syncthreads();
    }
    if (t < NBK) { boff[t] = s[t] - v; bcur[t] = s[t] - v; }
}

__global__ void bscatter(const int* __restrict__ esrc, const int* __restrict__ edst,
                         int* __restrict__ bcur, int2* __restrict__ eb) {
    int e = blockIdx.x * 256 + threadIdx.x;
    if (e < NE) {
        int d = edst[e];
        int p = atomicAdd(&bcur[d >> BSH], 1);
        eb[p] = make_int2(esrc[e], d);
    }
}

__global__ void bucket_csr(const int2* __restrict__ eb, const int* __restrict__ boff,
                           int* __restrict__ offs, int* __restrict__ perm) {
    __shared__ int deg[128], cur[128];
    const int b = blockIdx.x;
    const int n0 = b << BSH;
    int nN = NN - n0; if (nN > 128) nN = 128;
    const int e0 = boff[b];
    const int e1 = (b == NBK - 1) ? NE : boff[b + 1];
    if (threadIdx.x < 128) deg[threadIdx.x] = 0;
    __syncthreads();
    for (int i = e0 + threadIdx.x; i < e1; i += 256)
        atomicAdd(&deg[eb[i].y & 127], 1);
    __syncthreads();
    if (threadIdx.x == 0) {
        int run = e0;
        for (int i = 0; i < nN; ++i) { cur[i] = run; run += deg[i]; }
    }
    __syncthreads();
    if (threadIdx.x < nN) offs[n0 + threadIdx.x] = cur[threadIdx.x];
    __syncthreads();
    for (int i = e0 + threadIdx.x; i < e1; i += 256) {
        int2 e = eb[i];
        int pos = atomicAdd(&cur[e.y & 127], 1);
        perm[pos] = e.x;
    }
}

// ---------------------------------------------------------------------------
// fp32 -> bf16 convert (x once per call)
__global__ void to_bf16(const float* __restrict__ x, unsigned* __restrict__ xb) {
    size_t i = ((size_t)blockIdx.x * 256 + threadIdx.x) * 4;
    float4 v = *(const float4*)(x + i);
    uint2 o;
    o.x = f2bf(v.x) | (f2bf(v.y) << 16);
    o.y = f2bf(v.z) | (f2bf(v.w) << 16);
    *(uint2*)(xb + i / 2) = o;
}

// Build Wt[mat][n][k] bf16 from 8 fp32 weight matrices (once per call).
__global__ void build_wt(const float* __restrict__ W1, const float* __restrict__ W2,
                         unsigned short* __restrict__ Wt) {
    int b = blockIdx.x;              // 0..7: layer = b>>1, which = b&1
    const float* W = ((b & 1) ? W2 : W1) + (size_t)(b >> 1) * DIM * DIM;
    unsigned short* O = Wt + (size_t)b * DIM * DIM;
    int i = blockIdx.y * 2048 + threadIdx.x;
    for (int j = 0; j < 8; ++j, i += 256) {
        int k = i >> 7, n = i & 127;
        O[n * DIM + k] = (unsigned short)f2bf(W[i]);
    }
}

// ---------------------------------------------------------------------------
// Pull aggregation in bf16: out[n] = (1+eps)*T(h[n]) + sum_{src} T(h[src]).
// 256 threads = 4 nodes x 64 lanes; lane owns feature pair (2*lane, 2*lane+1).
template<int TR>
__global__ void csr_agg(const unsigned* __restrict__ hq, const int* __restrict__ offs,
                        const int* __restrict__ perm, const float* __restrict__ eps, int l,
                        const float* __restrict__ ta, const float* __restrict__ tc,
                        unsigned* __restrict__ outq) {
    int node = blockIdx.x * 4 + (threadIdx.x >> 6);
    int lane = threadIdx.x & 63;
    if (node >= NN) return;
    int start = offs[node];
    int end = (node == NN - 1) ? NE : offs[node + 1];
    int f = lane * 2;
    float a0 = 0.f, c0 = 0.f, a1 = 0.f, c1 = 0.f;
    if (TR) { a0 = ta[f]; c0 = tc[f]; a1 = ta[f + 1]; c1 = tc[f + 1]; }
    unsigned v = hq[(size_t)node * 64 + lane];
    float x0 = bf_lo(v), x1 = bf_hi(v);
    if (TR) {
        x0 = fmaxf(fmaf(x0, a0, c0), 0.f);
        x1 = fmaxf(fmaf(x1, a1, c1), 0.f);
    }
    float e1 = 1.0f + eps[l];
    float acc0 = e1 * x0, acc1 = e1 * x1;
    int j = start;
    for (; j + 3 < end; j += 4) {
        int s0 = perm[j], s1 = perm[j + 1], s2 = perm[j + 2], s3 = perm[j + 3];
        unsigned u0 = hq[(size_t)s0 * 64 + lane];
        unsigned u1 = hq[(size_t)s1 * 64 + lane];
        unsigned u2 = hq[(size_t)s2 * 64 + lane];
        unsigned u3 = hq[(size_t)s3 * 64 + lane];
        float p0 = bf_lo(u0), p1 = bf_hi(u0), p2 = bf_lo(u1), p3 = bf_hi(u1);
        float p4 = bf_lo(u2), p5 = bf_hi(u2), p6 = bf_lo(u3), p7 = bf_hi(u3);
        if (TR) {
            p0 = fmaxf(fmaf(p0, a0, c0), 0.f); p1 = fmaxf(fmaf(p1, a1, c1), 0.f);
            p2 = fmaxf(fmaf(p2, a0, c0), 0.f); p3 = fmaxf(fmaf(p3, a1, c1), 0.f);
            p4 = fmaxf(fmaf(p4, a0, c0), 0.f); p5 = fmaxf(fmaf(p5, a1, c1), 0.f);
            p6 = fmaxf(fmaf(p6, a0, c0), 0.f); p7 = fmaxf(fmaf(p7, a1, c1), 0.f);
        }
        acc0 += (p0 + p2) + (p4 + p6);
        acc1 += (p1 + p3) + (p5 + p7);
    }
    for (; j < end; ++j) {
        unsigned u0 = hq[(size_t)perm[j] * 64 + lane];
        float p0 = bf_lo(u0), p1 = bf_hi(u0);
        if (TR) {
            p0 = fmaxf(fmaf(p0, a0, c0), 0.f);
            p1 = fmaxf(fmaf(p1, a1, c1), 0.f);
        }
        acc0 += p0; acc1 += p1;
    }
    outq[(size_t)node * 64 + lane] = f2bf(acc0) | (f2bf(acc1) << 16);
}

// ---------------------------------------------------------------------------
// Y[NN x 128] = T(X) @ W + bias via mfma_f32_16x16x32_bf16, no LDS staging.
__global__ __launch_bounds__(256, 2)
void gemm_mfma(const unsigned short* __restrict__ X, const unsigned short* __restrict__ Wt,
               const float* __restrict__ bias,
               const float* __restrict__ ta, const float* __restrict__ tc,
               unsigned short* __restrict__ Y, float* __restrict__ stat) {
    __shared__ float red[4 * 256];
    const int t = threadIdx.x;
    const int w = t >> 6, lane = t & 63;
    const int quad = lane >> 4, m = lane & 15;
    const int rowbase = blockIdx.x * 128 + w * 32;
    const bool tr = (ta != nullptr);

    bf16x8 a[2][4];
#pragma unroll
    for (int rt = 0; rt < 2; ++rt) {
        int row = rowbase + rt * 16 + m;
        if (row > NN - 1) row = NN - 1;
        const unsigned short* xr = X + (size_t)row * DIM + quad * 8;
#pragma unroll
        for (int ks = 0; ks < 4; ++ks) {
            bf16x8 v = *(const bf16x8*)(xr + ks * 32);
            if (tr) {
                int kk = ks * 32 + quad * 8;
#pragma unroll
                for (int j = 0; j < 8; ++j) {
                    float fv = bfs2f(v[j]);
                    fv = fmaxf(fmaf(fv, ta[kk + j], tc[kk + j]), 0.f);
                    v[j] = (short)f2bf(fv);
                }
            }
            a[rt][ks] = v;
        }
    }

    floatx4 acc[2][8];
#pragma unroll
    for (int rt = 0; rt < 2; ++rt)
#pragma unroll
        for (int ct = 0; ct < 8; ++ct) acc[rt][ct] = (floatx4)0.f;

#pragma unroll
    for (int ct = 0; ct < 8; ++ct) {
        const unsigned short* wr = Wt + (size_t)(ct * 16 + m) * DIM + quad * 8;
#pragma unroll
        for (int ks = 0; ks < 4; ++ks) {
            bf16x8 b = *(const bf16x8*)(wr + ks * 32);
            acc[0][ct] = __builtin_amdgcn_mfma_f32_16x16x32_bf16(a[0][ks], b, acc[0][ct], 0, 0, 0);
            acc[1][ct] = __builtin_amdgcn_mfma_f32_16x16x32_bf16(a[1][ks], b, acc[1][ct], 0, 0, 0);
        }
    }

    // epilogue: bias + bf16 store + masked column stats
#pragma unroll
    for (int ct = 0; ct < 8; ++ct) {
        int col = ct * 16 + m;
        float bv = bias[col];
        float s = 0.f, q = 0.f;
#pragma unroll
        for (int rt = 0; rt < 2; ++rt) {
#pragma unroll
            for (int r = 0; r < 4; ++r) {
                int row = rowbase + rt * 16 + quad * 4 + r;
                float val = acc[rt][ct][r] + bv;
                if (row < NN) {
                    Y[(size_t)row * DIM + col] = (unsigned short)f2bf(val);
                    s += val;
                    q = fmaf(val, val, q);
                }
            }
        }
        s += __shfl_xor(s, 16); s += __shfl_xor(s, 32);
        q += __shfl_xor(q, 16); q += __shfl_xor(q, 32);
        if (quad == 0) { red[w * 256 + col] = s; red[w * 256 + 128 + col] = q; }
    }
    __syncthreads();
    if (t < 256) {
        float tot = red[t] + red[256 + t] + red[512 + t] + red[768 + t];
        unsafeAtomicAdd(&stat[t], tot);
    }
}

// Fold BN(train) + affine into x' = a*x + c per feature.
__global__ void bn_finalize(const float* __restrict__ stat,
                            const float* __restrict__ gamma, const float* __restrict__ beta,
                            int l, float* __restrict__ ta, float* __restrict__ tc) {
    int f = threadIdx.x;
    float mu = stat[f] * (1.0f / NN);
    float var = fmaf(-mu, mu, stat[DIM + f] * (1.0f / NN));
    float rstd = rsqrtf(var + 1e-5f);
    float a = gamma[l * DIM + f] * rstd;
    ta[f] = a;
    tc[f] = fmaf(-mu, a, beta[l * DIM + f]);
}

// Per-graph sum pooling (sorted graph_ids), bf16 input, fp32 accumulation.
// 32 nodes/block for occupancy (3125 blocks).
template<int TR>
__global__ void pool_nodes(const unsigned* __restrict__ hq, const int* __restrict__ gid,
                           const float* __restrict__ ta, const float* __restrict__ tc,
                           float* __restrict__ pg) {
    const int lane = threadIdx.x;            // 64 threads, feature pair per lane
    int start = blockIdx.x * 32;
    int end = start + 32;
    if (end > NN) end = NN;
    int f = lane * 2;
    float a0 = 0.f, c0 = 0.f, a1 = 0.f, c1 = 0.f;
    if (TR) { a0 = ta[f]; c0 = tc[f]; a1 = ta[f + 1]; c1 = tc[f + 1]; }
    int cur = gid[start];
    float acc0 = 0.f, acc1 = 0.f;
    for (int i = start; i < end; ++i) {
        int g = gid[i];
        if (g != cur) {
            unsafeAtomicAdd(&pg[cur * DIM + f], acc0);
            unsafeAtomicAdd(&pg[cur * DIM + f + 1], acc1);
            acc0 = 0.f; acc1 = 0.f;
            cur = g;
        }
        unsigned u = hq[(size_t)i * 64 + lane];
        float x0 = bf_lo(u), x1 = bf_hi(u);
        if (TR) {
            x0 = fmaxf(fmaf(x0, a0, c0), 0.f);
            x1 = fmaxf(fmaf(x1, a1, c1), 0.f);
        }
        acc0 += x0; acc1 += x1;
    }
    unsafeAtomicAdd(&pg[cur * DIM + f], acc0);
    unsafeAtomicAdd(&pg[cur * DIM + f + 1], acc1);
}

__global__ void final_score(const float* __restrict__ pg, const float* __restrict__ predW,
                            const float* __restrict__ predb, float* __restrict__ out) {
    int g = blockIdx.x;
    int o = threadIdx.x;
    float acc = 0.f;
    for (int l = 0; l <= NL; ++l) {
        acc += predb[l * OUTD + o];
        const float* pgr = pg + ((size_t)l * NG + g) * DIM;
        const float* w = predW + (size_t)l * DIM * OUTD;
#pragma unroll 8
        for (int k = 0; k < DIM; ++k)
            acc = fmaf(pgr[k], w[k * OUTD + o], acc);
    }
    out[g * OUTD + o] = acc;
}

extern "C" void kernel_launch(void* const* d_in, const int* in_sizes, int n_in,
                              void* d_out, int out_size, void* d_ws, size_t ws_size,
                              hipStream_t stream) {
    const float* x     = (const float*)d_in[0];
    const int*   esrc  = (const int*)d_in[1];
    const int*   edst  = (const int*)d_in[2];
    const int*   gid   = (const int*)d_in[3];
    const float* eps   = (const float*)d_in[4];
    const float* W1    = (const float*)d_in[5];
    const float* b1    = (const float*)d_in[6];
    const float* g1    = (const float*)d_in[7];
    const float* be1   = (const float*)d_in[8];
    const float* W2    = (const float*)d_in[9];
    const float* b2    = (const float*)d_in[10];
    const float* g2    = (const float*)d_in[11];
    const float* be2   = (const float*)d_in[12];
    const float* predW = (const float*)d_in[13];
    const float* predb = (const float*)d_in[14];
    float* out = (float*)d_out;

    // ws layout (~95 MB): 3 bf16 node buffers + Wt + PG + stats + CSR arrays
    unsigned short* XB = (unsigned short*)d_ws;
    unsigned short* A  = XB + (size_t)NN * DIM;
    unsigned short* B  = A + (size_t)NN * DIM;
    unsigned short* WT = B + (size_t)NN * DIM;
    float* PG   = (float*)(WT + 8 * DIM * DIM);
    float* STAT = PG + 5 * NG * DIM;          // 512 floats: [S1|SQ1 | S2|SQ2]
    float* TA1  = STAT + 512;
    float* TC1  = TA1 + DIM;
    float* TA2  = TC1 + DIM;
    float* TC2  = TA2 + DIM;
    int* BCNT = (int*)(TC2 + DIM);
    int* BOFF = BCNT + NBK;
    int* BCUR = BOFF + NBK;
    int* OFFS = BCUR + NBK;
    int* PERM = OFFS + NN;
    int2* EB  = (int2*)(PERM + NE);

    hipMemsetAsync(PG, 0, 5 * NG * DIM * sizeof(float), stream);
    hipMemsetAsync(BCNT, 0, NBK * sizeof(int), stream);

    // ---- one-time per call: bucketed CSR build, x->bf16, transposed weights
    bhist<<<(NE + 4095) / 4096, 256, 0, stream>>>(edst, BCNT);
    bscan<<<1, 1024, 0, stream>>>(BCNT, BOFF, BCUR);
    bscatter<<<(NE + 255) / 256, 256, 0, stream>>>(esrc, edst, BCUR, EB);
    bucket_csr<<<NBK, 256, 0, stream>>>(EB, BOFF, OFFS, PERM);
    to_bf16<<<(NN * DIM) / 1024, 256, 0, stream>>>(x, (unsigned*)XB);
    build_wt<<<dim3(8, 8), 256, 0, stream>>>(W1, W2, WT);

    const int poolBlocks = (NN + 31) / 32;
    const int aggBlocks  = (NN + 3) / 4;
    const int gemmBlocks = (NN + 127) / 128;

    const unsigned* h = (const unsigned*)XB;
    for (int l = 0; l < NL; ++l) {
        if (l == 0) {
            pool_nodes<0><<<poolBlocks, 64, 0, stream>>>(h, gid, nullptr, nullptr, PG);
            csr_agg<0><<<aggBlocks, 256, 0, stream>>>(h, OFFS, PERM, eps, l,
                                                      nullptr, nullptr, (unsigned*)B);
        } else {
            pool_nodes<1><<<poolBlocks, 64, 0, stream>>>(h, gid, TA2, TC2, PG + l * NG * DIM);
            csr_agg<1><<<aggBlocks, 256, 0, stream>>>(h, OFFS, PERM, eps, l,
                                                      TA2, TC2, (unsigned*)B);
        }
        hipMemsetAsync(STAT, 0, 512 * sizeof(float), stream);
        gemm_mfma<<<gemmBlocks, 256, 0, stream>>>(B, WT + (size_t)(2 * l) * DIM * DIM,
                                                  b1 + l * DIM, nullptr, nullptr, B, STAT);
        bn_finalize<<<1, DIM, 0, stream>>>(STAT, g1, be1, l, TA1, TC1);
        gemm_mfma<<<gemmBlocks, 256, 0, stream>>>(B, WT + (size_t)(2 * l + 1) * DIM * DIM,
                                                  b2 + l * DIM, TA1, TC1, A, STAT + 256);
        bn_finalize<<<1, DIM, 0, stream>>>(STAT + 256, g2, be2, l, TA2, TC2);
        h = (const unsigned*)A;
    }
    pool_nodes<1><<<poolBlocks, 64, 0, stream>>>(h, gid, TA2, TC2, PG + NL * NG * DIM);
    final_score<<<NG, OUTD, 0, stream>>>(PG, predW, predb, out);
}

// Round 5
// 1118.522 us; speedup vs baseline: 4.1893x; 1.2976x over previous
//
#include <hip/hip_runtime.h>

#define NN 100000
#define NE 1600000
#define NG 128
#define DIM 128
#define OUTD 64
#define NL 4
#define SCAN_B 1024
#define NB ((NN + SCAN_B - 1) / SCAN_B)   // 98 scan blocks

typedef __attribute__((ext_vector_type(8))) short bf16x8;
typedef __attribute__((ext_vector_type(4))) float floatx4;

__device__ __forceinline__ float bf_lo(unsigned u) {
    union { unsigned u; float f; } c; c.u = u << 16; return c.f;
}
__device__ __forceinline__ float bf_hi(unsigned u) {
    union { unsigned u; float f; } c; c.u = u & 0xffff0000u; return c.f;
}
__device__ __forceinline__ unsigned f2bf(float x) {   // RNE
    union { float f; unsigned u; } c; c.f = x;
    return (c.u + 0x7fffu + ((c.u >> 16) & 1u)) >> 16;
}
__device__ __forceinline__ float bfs2f(short s) {
    union { unsigned u; float f; } c; c.u = ((unsigned)(unsigned short)s) << 16; return c.f;
}

// BN(train) fold: from stat = [sum(128) | sumsq(128)] derive a,c so that
// bn(x) = a*x + c.
__device__ __forceinline__ void bn_coef(const float* __restrict__ stat,
                                        const float* __restrict__ gamma,
                                        const float* __restrict__ beta,
                                        int f, float& a, float& c) {
    float mu = stat[f] * (1.0f / NN);
    float var = fmaf(-mu, mu, stat[DIM + f] * (1.0f / NN));
    a = gamma[f] * rsqrtf(var + 1e-5f);
    c = fmaf(-mu, a, beta[f]);
}

// ---------------------------------------------------------------------------
// CSR build, node-granular (R3 scheme: 100K cursors -> no atomic hot-spot)
__global__ void hist(const int* __restrict__ edst, int* __restrict__ deg) {
    int e = blockIdx.x * 256 + threadIdx.x;
    if (e < NE) atomicAdd(&deg[edst[e]], 1);
}

__global__ void scan_local(const int* __restrict__ deg, int* __restrict__ loc,
                           int* __restrict__ bsums) {
    __shared__ int s[256];
    int base = blockIdx.x * SCAN_B + threadIdx.x * 4;
    int d0 = 0, d1 = 0, d2 = 0, d3 = 0;
    if (base + 0 < NN) d0 = deg[base + 0];
    if (base + 1 < NN) d1 = deg[base + 1];
    if (base + 2 < NN) d2 = deg[base + 2];
    if (base + 3 < NN) d3 = deg[base + 3];
    int t4 = d0 + d1 + d2 + d3;
    s[threadIdx.x] = t4;
    __syncthreads();
    for (int off = 1; off < 256; off <<= 1) {
        int v = (threadIdx.x >= off) ? s[threadIdx.x - off] : 0;
        __syncthreads();
        s[threadIdx.x] += v;
        __syncthreads();
    }
    int excl = s[threadIdx.x] - t4;
    if (base + 0 < NN) loc[base + 0] = excl;
    if (base + 1 < NN) loc[base + 1] = excl + d0;
    if (base + 2 < NN) loc[base + 2] = excl + d0 + d1;
    if (base + 3 < NN) loc[base + 3] = excl + d0 + d1 + d2;
    if (threadIdx.x == 255) bsums[blockIdx.x] = s[255];
}

__global__ void scan_sums(int* __restrict__ bsums) {
    __shared__ int s[128];
    int v = (threadIdx.x < NB) ? bsums[threadIdx.x] : 0;
    s[threadIdx.x] = v;
    __syncthreads();
    for (int off = 1; off < 128; off <<= 1) {
        int u = (threadIdx.x >= off) ? s[threadIdx.x - off] : 0;
        __syncthreads();
        s[threadIdx.x] += u;
        __syncthreads();
    }
    if (threadIdx.x < NB) bsums[threadIdx.x] = s[threadIdx.x] - v;  // exclusive
}

__global__ void scan_add(const int* __restrict__ loc, const int* __restrict__ bsums,
                         int* __restrict__ offs, int* __restrict__ cur) {
    int i = blockIdx.x * 256 + threadIdx.x;
    if (i < NN) {
        int o = loc[i] + bsums[i >> 10];
        offs[i] = o;
        cur[i] = o;
    }
}

__global__ void scatter_edges(const int* __restrict__ esrc, const int* __restrict__ edst,
                              int* __restrict__ cur, int* __restrict__ perm) {
    int e = blockIdx.x * 256 + threadIdx.x;
    if (e < NE) {
        int pos = atomicAdd(&cur[edst[e]], 1);
        perm[pos] = esrc[e];
    }
}

// ---------------------------------------------------------------------------
// fp32 -> bf16 convert (x once per call)
__global__ void to_bf16(const float* __restrict__ x, unsigned* __restrict__ xb) {
    size_t i = ((size_t)blockIdx.x * 256 + threadIdx.x) * 4;
    float4 v = *(const float4*)(x + i);
    uint2 o;
    o.x = f2bf(v.x) | (f2bf(v.y) << 16);
    o.y = f2bf(v.z) | (f2bf(v.w) << 16);
    *(uint2*)(xb + i / 2) = o;
}

// Build Wt[mat][n][k] bf16 from 8 fp32 weight matrices (once per call).
__global__ void build_wt(const float* __restrict__ W1, const float* __restrict__ W2,
                         unsigned short* __restrict__ Wt) {
    int b = blockIdx.x;              // 0..7: layer = b>>1, which = b&1
    const float* W = ((b & 1) ? W2 : W1) + (size_t)(b >> 1) * DIM * DIM;
    unsigned short* O = Wt + (size_t)b * DIM * DIM;
    int i = blockIdx.y * 2048 + threadIdx.x;
    for (int j = 0; j < 8; ++j, i += 256) {
        int k = i >> 7, n = i & 127;
        O[n * DIM + k] = (unsigned short)f2bf(W[i]);
    }
}

// ---------------------------------------------------------------------------
// Pull aggregation in bf16: out[n] = (1+eps)*T(h[n]) + sum_{src} T(h[src]).
// 256 threads = 4 nodes x 64 lanes; lane owns feature pair (2*lane, 2*lane+1).
// T = BN2+ReLU of previous layer, derived in-register from stat/gamma/beta.
// 8-deep gather unroll for memory-level parallelism.
template<int TR>
__global__ void csr_agg(const unsigned* __restrict__ hq, const int* __restrict__ offs,
                        const int* __restrict__ perm, const float* __restrict__ eps, int l,
                        const float* __restrict__ stat, const float* __restrict__ gamma,
                        const float* __restrict__ beta, unsigned* __restrict__ outq) {
    int node = blockIdx.x * 4 + (threadIdx.x >> 6);
    int lane = threadIdx.x & 63;
    if (node >= NN) return;
    int start = offs[node];
    int end = (node == NN - 1) ? NE : offs[node + 1];
    int f = lane * 2;
    float a0 = 0.f, c0 = 0.f, a1 = 0.f, c1 = 0.f;
    if (TR) {
        bn_coef(stat, gamma, beta, f, a0, c0);
        bn_coef(stat, gamma, beta, f + 1, a1, c1);
    }
    unsigned v = hq[(size_t)node * 64 + lane];
    float x0 = bf_lo(v), x1 = bf_hi(v);
    if (TR) {
        x0 = fmaxf(fmaf(x0, a0, c0), 0.f);
        x1 = fmaxf(fmaf(x1, a1, c1), 0.f);
    }
    float e1 = 1.0f + eps[l];
    float acc0 = e1 * x0, acc1 = e1 * x1;
    int j = start;
    for (; j + 7 < end; j += 8) {
        unsigned u[8];
#pragma unroll
        for (int q = 0; q < 8; ++q)
            u[q] = hq[(size_t)perm[j + q] * 64 + lane];
        float s0 = 0.f, s1 = 0.f;
#pragma unroll
        for (int q = 0; q < 8; ++q) {
            float p0 = bf_lo(u[q]), p1 = bf_hi(u[q]);
            if (TR) {
                p0 = fmaxf(fmaf(p0, a0, c0), 0.f);
                p1 = fmaxf(fmaf(p1, a1, c1), 0.f);
            }
            s0 += p0; s1 += p1;
        }
        acc0 += s0; acc1 += s1;
    }
    for (; j < end; ++j) {
        unsigned u0 = hq[(size_t)perm[j] * 64 + lane];
        float p0 = bf_lo(u0), p1 = bf_hi(u0);
        if (TR) {
            p0 = fmaxf(fmaf(p0, a0, c0), 0.f);
            p1 = fmaxf(fmaf(p1, a1, c1), 0.f);
        }
        acc0 += p0; acc1 += p1;
    }
    outq[(size_t)node * 64 + lane] = f2bf(acc0) | (f2bf(acc1) << 16);
}

// ---------------------------------------------------------------------------
// Y[NN x 128] = T(X) @ W + bias via mfma_f32_16x16x32_bf16, no LDS staging.
// T = folded inner BN+ReLU computed cooperatively into LDS (TR=1).
// Fused epilogue: bf16 store + per-column sum/sumsq -> ostat[0:128]/[128:256].
template<int TR>
__global__ __launch_bounds__(256, 2)
void gemm_mfma(const unsigned short* __restrict__ X, const unsigned short* __restrict__ Wt,
               const float* __restrict__ bias,
               const float* __restrict__ stat, const float* __restrict__ gamma,
               const float* __restrict__ beta,
               unsigned short* __restrict__ Y, float* __restrict__ ostat) {
    __shared__ float red[4 * 256];
    __shared__ float tatc[2 * DIM];
    const int t = threadIdx.x;
    const int w = t >> 6, lane = t & 63;
    const int quad = lane >> 4, m = lane & 15;
    const int rowbase = blockIdx.x * 128 + w * 32;

    if (TR) {
        if (t < DIM) {
            float a, c;
            bn_coef(stat, gamma, beta, t, a, c);
            tatc[t] = a; tatc[DIM + t] = c;
        }
        __syncthreads();
    }

    bf16x8 a[2][4];
#pragma unroll
    for (int rt = 0; rt < 2; ++rt) {
        int row = rowbase + rt * 16 + m;
        if (row > NN - 1) row = NN - 1;
        const unsigned short* xr = X + (size_t)row * DIM + quad * 8;
#pragma unroll
        for (int ks = 0; ks < 4; ++ks) {
            bf16x8 v = *(const bf16x8*)(xr + ks * 32);
            if (TR) {
                int kk = ks * 32 + quad * 8;
#pragma unroll
                for (int j = 0; j < 8; ++j) {
                    float fv = bfs2f(v[j]);
                    fv = fmaxf(fmaf(fv, tatc[kk + j], tatc[DIM + kk + j]), 0.f);
                    v[j] = (short)f2bf(fv);
                }
            }
            a[rt][ks] = v;
        }
    }

    floatx4 acc[2][8];
#pragma unroll
    for (int rt = 0; rt < 2; ++rt)
#pragma unroll
        for (int ct = 0; ct < 8; ++ct) acc[rt][ct] = (floatx4)0.f;

#pragma unroll
    for (int ct = 0; ct < 8; ++ct) {
        const unsigned short* wr = Wt + (size_t)(ct * 16 + m) * DIM + quad * 8;
#pragma unroll
        for (int ks = 0; ks < 4; ++ks) {
            bf16x8 b = *(const bf16x8*)(wr + ks * 32);
            acc[0][ct] = __builtin_amdgcn_mfma_f32_16x16x32_bf16(a[0][ks], b, acc[0][ct], 0, 0, 0);
            acc[1][ct] = __builtin_amdgcn_mfma_f32_16x16x32_bf16(a[1][ks], b, acc[1][ct], 0, 0, 0);
        }
    }

    // epilogue: bias + bf16 store + masked column stats
#pragma unroll
    for (int ct = 0; ct < 8; ++ct) {
        int col = ct * 16 + m;
        float bv = bias[col];
        float s = 0.f, q = 0.f;
#pragma unroll
        for (int rt = 0; rt < 2; ++rt) {
#pragma unroll
            for (int r = 0; r < 4; ++r) {
                int row = rowbase + rt * 16 + quad * 4 + r;
                float val = acc[rt][ct][r] + bv;
                if (row < NN) {
                    Y[(size_t)row * DIM + col] = (unsigned short)f2bf(val);
                    s += val;
                    q = fmaf(val, val, q);
                }
            }
        }
        s += __shfl_xor(s, 16); s += __shfl_xor(s, 32);
        q += __shfl_xor(q, 16); q += __shfl_xor(q, 32);
        if (quad == 0) { red[w * 256 + col] = s; red[w * 256 + 128 + col] = q; }
    }
    __syncthreads();
    if (t < 256) {
        float tot = red[t] + red[256 + t] + red[512 + t] + red[768 + t];
        unsafeAtomicAdd(&ostat[t], tot);
    }
}

// Per-graph sum pooling (sorted graph_ids), bf16 input, fp32 accumulation.
// 32 nodes/block (3125 blocks). BN fold in-register (TR=1).
template<int TR>
__global__ void pool_nodes(const unsigned* __restrict__ hq, const int* __restrict__ gid,
                           const float* __restrict__ stat, const float* __restrict__ gamma,
                           const float* __restrict__ beta, float* __restrict__ pg) {
    const int lane = threadIdx.x;            // 64 threads, feature pair per lane
    int start = blockIdx.x * 32;
    int end = start + 32;
    if (end > NN) end = NN;
    int f = lane * 2;
    float a0 = 0.f, c0 = 0.f, a1 = 0.f, c1 = 0.f;
    if (TR) {
        bn_coef(stat, gamma, beta, f, a0, c0);
        bn_coef(stat, gamma, beta, f + 1, a1, c1);
    }
    int cur = gid[start];
    float acc0 = 0.f, acc1 = 0.f;
    for (int i = start; i < end; ++i) {
        int g = gid[i];
        if (g != cur) {
            unsafeAtomicAdd(&pg[cur * DIM + f], acc0);
            unsafeAtomicAdd(&pg[cur * DIM + f + 1], acc1);
            acc0 = 0.f; acc1 = 0.f;
            cur = g;
        }
        unsigned u = hq[(size_t)i * 64 + lane];
        float x0 = bf_lo(u), x1 = bf_hi(u);
        if (TR) {
            x0 = fmaxf(fmaf(x0, a0, c0), 0.f);
            x1 = fmaxf(fmaf(x1, a1, c1), 0.f);
        }
        acc0 += x0; acc1 += x1;
    }
    unsafeAtomicAdd(&pg[cur * DIM + f], acc0);
    unsafeAtomicAdd(&pg[cur * DIM + f + 1], acc1);
}

__global__ void final_score(const float* __restrict__ pg, const float* __restrict__ predW,
                            const float* __restrict__ predb, float* __restrict__ out) {
    int g = blockIdx.x;
    int o = threadIdx.x;
    float acc = 0.f;
    for (int l = 0; l <= NL; ++l) {
        acc += predb[l * OUTD + o];
        const float* pgr = pg + ((size_t)l * NG + g) * DIM;
        const float* w = predW + (size_t)l * DIM * OUTD;
#pragma unroll 8
        for (int k = 0; k < DIM; ++k)
            acc = fmaf(pgr[k], w[k * OUTD + o], acc);
    }
    out[g * OUTD + o] = acc;
}

extern "C" void kernel_launch(void* const* d_in, const int* in_sizes, int n_in,
                              void* d_out, int out_size, void* d_ws, size_t ws_size,
                              hipStream_t stream) {
    const float* x     = (const float*)d_in[0];
    const int*   esrc  = (const int*)d_in[1];
    const int*   edst  = (const int*)d_in[2];
    const int*   gid   = (const int*)d_in[3];
    const float* eps   = (const float*)d_in[4];
    const float* W1    = (const float*)d_in[5];
    const float* b1    = (const float*)d_in[6];
    const float* g1    = (const float*)d_in[7];
    const float* be1   = (const float*)d_in[8];
    const float* W2    = (const float*)d_in[9];
    const float* b2    = (const float*)d_in[10];
    const float* g2    = (const float*)d_in[11];
    const float* be2   = (const float*)d_in[12];
    const float* predW = (const float*)d_in[13];
    const float* predb = (const float*)d_in[14];
    float* out = (float*)d_out;

    // ws layout (~85 MB): 3 bf16 node buffers + Wt + PG + stats + CSR arrays
    unsigned short* XB = (unsigned short*)d_ws;
    unsigned short* A  = XB + (size_t)NN * DIM;
    unsigned short* B  = A + (size_t)NN * DIM;
    unsigned short* WT = B + (size_t)NN * DIM;
    float* PG   = (float*)(WT + 8 * DIM * DIM);
    float* STAT = PG + 5 * NG * DIM;          // 512 floats: [S1|SQ1 | S2|SQ2]
    int* DEG  = (int*)(STAT + 512);
    int* LOC  = DEG + NN;
    int* OFFS = LOC + NN;
    int* CUR  = OFFS + NN;
    int* BS   = CUR + NN;
    int* PERM = BS + 128;

    hipMemsetAsync(PG, 0, 5 * NG * DIM * sizeof(float), stream);
    hipMemsetAsync(DEG, 0, NN * sizeof(int), stream);

    // ---- one-time per call: CSR build, x->bf16, transposed bf16 weights
    const int eBlocks = (NE + 255) / 256;
    hist<<<eBlocks, 256, 0, stream>>>(edst, DEG);
    scan_local<<<NB, 256, 0, stream>>>(DEG, LOC, BS);
    scan_sums<<<1, 128, 0, stream>>>(BS);
    scan_add<<<(NN + 255) / 256, 256, 0, stream>>>(LOC, BS, OFFS, CUR);
    scatter_edges<<<eBlocks, 256, 0, stream>>>(esrc, edst, CUR, PERM);
    to_bf16<<<(NN * DIM) / 1024, 256, 0, stream>>>(x, (unsigned*)XB);
    build_wt<<<dim3(8, 8), 256, 0, stream>>>(W1, W2, WT);

    const int poolBlocks = (NN + 31) / 32;
    const int aggBlocks  = (NN + 3) / 4;
    const int gemmBlocks = (NN + 127) / 128;

    const unsigned* h = (const unsigned*)XB;
    for (int l = 0; l < NL; ++l) {
        if (l == 0) {
            pool_nodes<0><<<poolBlocks, 64, 0, stream>>>(h, gid, nullptr, nullptr, nullptr, PG);
            csr_agg<0><<<aggBlocks, 256, 0, stream>>>(h, OFFS, PERM, eps, l,
                                                      nullptr, nullptr, nullptr, (unsigned*)B);
        } else {
            const float* gg = g2 + (l - 1) * DIM;
            const float* bb = be2 + (l - 1) * DIM;
            pool_nodes<1><<<poolBlocks, 64, 0, stream>>>(h, gid, STAT + 256, gg, bb,
                                                         PG + l * NG * DIM);
            csr_agg<1><<<aggBlocks, 256, 0, stream>>>(h, OFFS, PERM, eps, l,
                                                      STAT + 256, gg, bb, (unsigned*)B);
        }
        hipMemsetAsync(STAT, 0, 512 * sizeof(float), stream);
        gemm_mfma<0><<<gemmBlocks, 256, 0, stream>>>(B, WT + (size_t)(2 * l) * DIM * DIM,
                                                     b1 + l * DIM, nullptr, nullptr, nullptr,
                                                     B, STAT);
        gemm_mfma<1><<<gemmBlocks, 256, 0, stream>>>(B, WT + (size_t)(2 * l + 1) * DIM * DIM,
                                                     b2 + l * DIM, STAT, g1 + l * DIM,
                                                     be1 + l * DIM, A, STAT + 256);
        h = (const unsigned*)A;
    }
    pool_nodes<1><<<poolBlocks, 64, 0, stream>>>(h, gid, STAT + 256, g2 + (NL - 1) * DIM,
                                                 be2 + (NL - 1) * DIM, PG + NL * NG * DIM);
    final_score<<<NG, OUTD, 0, stream>>>(PG, predW, predb, out);
}

// Round 6
// 1063.402 us; speedup vs baseline: 4.4064x; 1.0518x over previous
//
#include <hip/hip_runtime.h>

#define NN 100000
#define NE 1600000
#define NG 128
#define DIM 128
#define OUTD 64
#define NL 4
#define SCAN_B 1024
#define NB ((NN + SCAN_B - 1) / SCAN_B)   // 98 scan blocks
#define NSL 8                              // XCD slices for scatter
#define SLN 12500                          // nodes per slice (8*12500 = 100000)
#define SL_CH 4096                         // edges per scatter chunk

typedef __attribute__((ext_vector_type(8))) short bf16x8;
typedef __attribute__((ext_vector_type(4))) float floatx4;

__device__ __forceinline__ float bf_lo(unsigned u) {
    union { unsigned u; float f; } c; c.u = u << 16; return c.f;
}
__device__ __forceinline__ float bf_hi(unsigned u) {
    union { unsigned u; float f; } c; c.u = u & 0xffff0000u; return c.f;
}
__device__ __forceinline__ unsigned f2bf(float x) {   // RNE
    union { float f; unsigned u; } c; c.f = x;
    return (c.u + 0x7fffu + ((c.u >> 16) & 1u)) >> 16;
}
__device__ __forceinline__ float bfs2f(short s) {
    union { unsigned u; float f; } c; c.u = ((unsigned)(unsigned short)s) << 16; return c.f;
}

// BN(train) fold: from stat = [sum(128) | sumsq(128)] derive a,c so that
// bn(x) = a*x + c.
__device__ __forceinline__ void bn_coef(const float* __restrict__ stat,
                                        const float* __restrict__ gamma,
                                        const float* __restrict__ beta,
                                        int f, float& a, float& c) {
    float mu = stat[f] * (1.0f / NN);
    float var = fmaf(-mu, mu, stat[DIM + f] * (1.0f / NN));
    a = gamma[f] * rsqrtf(var + 1e-5f);
    c = fmaf(-mu, a, beta[f]);
}

// ---------------------------------------------------------------------------
// CSR build, node-granular cursors (100K counters -> no atomic hot-spot)
__global__ void hist(const int* __restrict__ edst, int* __restrict__ deg) {
    int e = blockIdx.x * 256 + threadIdx.x;
    if (e < NE) atomicAdd(&deg[edst[e]], 1);
}

__global__ void scan_local(const int* __restrict__ deg, int* __restrict__ loc,
                           int* __restrict__ bsums) {
    __shared__ int s[256];
    int base = blockIdx.x * SCAN_B + threadIdx.x * 4;
    int d0 = 0, d1 = 0, d2 = 0, d3 = 0;
    if (base + 0 < NN) d0 = deg[base + 0];
    if (base + 1 < NN) d1 = deg[base + 1];
    if (base + 2 < NN) d2 = deg[base + 2];
    if (base + 3 < NN) d3 = deg[base + 3];
    int t4 = d0 + d1 + d2 + d3;
    s[threadIdx.x] = t4;
    __syncthreads();
    for (int off = 1; off < 256; off <<= 1) {
        int v = (threadIdx.x >= off) ? s[threadIdx.x - off] : 0;
        __syncthreads();
        s[threadIdx.x] += v;
        __syncthreads();
    }
    int excl = s[threadIdx.x] - t4;
    if (base + 0 < NN) loc[base + 0] = excl;
    if (base + 1 < NN) loc[base + 1] = excl + d0;
    if (base + 2 < NN) loc[base + 2] = excl + d0 + d1;
    if (base + 3 < NN) loc[base + 3] = excl + d0 + d1 + d2;
    if (threadIdx.x == 255) bsums[blockIdx.x] = s[255];
}

__global__ void scan_sums(int* __restrict__ bsums) {
    __shared__ int s[128];
    int v = (threadIdx.x < NB) ? bsums[threadIdx.x] : 0;
    s[threadIdx.x] = v;
    __syncthreads();
    for (int off = 1; off < 128; off <<= 1) {
        int u = (threadIdx.x >= off) ? s[threadIdx.x - off] : 0;
        __syncthreads();
        s[threadIdx.x] += u;
        __syncthreads();
    }
    if (threadIdx.x < NB) bsums[threadIdx.x] = s[threadIdx.x] - v;  // exclusive
}

__global__ void scan_add(const int* __restrict__ loc, const int* __restrict__ bsums,
                         int* __restrict__ offs, int* __restrict__ cur) {
    int i = blockIdx.x * 256 + threadIdx.x;
    if (i < NN) {
        int o = loc[i] + bsums[i >> 10];
        offs[i] = o;
        cur[i] = o;
    }
}

// XCD-sliced scatter: blockIdx.x = slice (round-robin linear-block->XCD puts
// each slice on one XCD); slice s only scatters edges with dst in its 12500-
// node range, so its ~800KB perm window stays L2-resident until lines fill.
__global__ void scatter_sliced(const int* __restrict__ esrc, const int* __restrict__ edst,
                               int* __restrict__ cur, int* __restrict__ perm) {
    const unsigned lo = blockIdx.x * SLN, hi = lo + SLN;
    int base = blockIdx.y * SL_CH;
    int end = base + SL_CH; if (end > NE) end = NE;
    for (int e = base + threadIdx.x; e < end; e += 256) {
        unsigned d = (unsigned)edst[e];
        if (d >= lo && d < hi) {
            int pos = atomicAdd(&cur[d], 1);
            perm[pos] = esrc[e];
        }
    }
}

// ---------------------------------------------------------------------------
// fp32 -> bf16 convert (x once per call)
__global__ void to_bf16(const float* __restrict__ x, unsigned* __restrict__ xb) {
    size_t i = ((size_t)blockIdx.x * 256 + threadIdx.x) * 4;
    float4 v = *(const float4*)(x + i);
    uint2 o;
    o.x = f2bf(v.x) | (f2bf(v.y) << 16);
    o.y = f2bf(v.z) | (f2bf(v.w) << 16);
    *(uint2*)(xb + i / 2) = o;
}

// Build Wt[mat][n][k] bf16 from 8 fp32 weight matrices (once per call).
__global__ void build_wt(const float* __restrict__ W1, const float* __restrict__ W2,
                         unsigned short* __restrict__ Wt) {
    int b = blockIdx.x;              // 0..7: layer = b>>1, which = b&1
    const float* W = ((b & 1) ? W2 : W1) + (size_t)(b >> 1) * DIM * DIM;
    unsigned short* O = Wt + (size_t)b * DIM * DIM;
    int i = blockIdx.y * 2048 + threadIdx.x;
    for (int j = 0; j < 8; ++j, i += 256) {
        int k = i >> 7, n = i & 127;
        O[n * DIM + k] = (unsigned short)f2bf(W[i]);
    }
}

// ---------------------------------------------------------------------------
// Pull aggregation in bf16: out[n] = (1+eps)*T(h[n]) + sum_{src} T(h[src]).
// 256 threads = 4 nodes x 64 lanes; lane owns feature pair (2*lane, 2*lane+1).
// T = BN2+ReLU of previous layer, derived in-register from stat/gamma/beta.
// 8-deep gather unroll for memory-level parallelism.
template<int TR>
__global__ void csr_agg(const unsigned* __restrict__ hq, const int* __restrict__ offs,
                        const int* __restrict__ perm, const float* __restrict__ eps, int l,
                        const float* __restrict__ stat, const float* __restrict__ gamma,
                        const float* __restrict__ beta, unsigned* __restrict__ outq) {
    int node = blockIdx.x * 4 + (threadIdx.x >> 6);
    int lane = threadIdx.x & 63;
    if (node >= NN) return;
    int start = offs[node];
    int end = (node == NN - 1) ? NE : offs[node + 1];
    int f = lane * 2;
    float a0 = 0.f, c0 = 0.f, a1 = 0.f, c1 = 0.f;
    if (TR) {
        bn_coef(stat, gamma, beta, f, a0, c0);
        bn_coef(stat, gamma, beta, f + 1, a1, c1);
    }
    unsigned v = hq[(size_t)node * 64 + lane];
    float x0 = bf_lo(v), x1 = bf_hi(v);
    if (TR) {
        x0 = fmaxf(fmaf(x0, a0, c0), 0.f);
        x1 = fmaxf(fmaf(x1, a1, c1), 0.f);
    }
    float e1 = 1.0f + eps[l];
    float acc0 = e1 * x0, acc1 = e1 * x1;
    int j = start;
    for (; j + 7 < end; j += 8) {
        unsigned u[8];
#pragma unroll
        for (int q = 0; q < 8; ++q)
            u[q] = hq[(size_t)perm[j + q] * 64 + lane];
        float s0 = 0.f, s1 = 0.f;
#pragma unroll
        for (int q = 0; q < 8; ++q) {
            float p0 = bf_lo(u[q]), p1 = bf_hi(u[q]);
            if (TR) {
                p0 = fmaxf(fmaf(p0, a0, c0), 0.f);
                p1 = fmaxf(fmaf(p1, a1, c1), 0.f);
            }
            s0 += p0; s1 += p1;
        }
        acc0 += s0; acc1 += s1;
    }
    for (; j < end; ++j) {
        unsigned u0 = hq[(size_t)perm[j] * 64 + lane];
        float p0 = bf_lo(u0), p1 = bf_hi(u0);
        if (TR) {
            p0 = fmaxf(fmaf(p0, a0, c0), 0.f);
            p1 = fmaxf(fmaf(p1, a1, c1), 0.f);
        }
        acc0 += p0; acc1 += p1;
    }
    outq[(size_t)node * 64 + lane] = f2bf(acc0) | (f2bf(acc1) << 16);
}

// ---------------------------------------------------------------------------
// Y[NN x 128] = T(X) @ W + bias via mfma_f32_16x16x32_bf16, no LDS staging.
// T = folded inner BN+ReLU computed cooperatively into LDS (TR=1).
// Fused epilogue: bf16 store + per-column sum/sumsq -> ostat[0:128]/[128:256].
template<int TR>
__global__ __launch_bounds__(256, 2)
void gemm_mfma(const unsigned short* __restrict__ X, const unsigned short* __restrict__ Wt,
               const float* __restrict__ bias,
               const float* __restrict__ stat, const float* __restrict__ gamma,
               const float* __restrict__ beta,
               unsigned short* __restrict__ Y, float* __restrict__ ostat) {
    __shared__ float red[4 * 256];
    __shared__ float tatc[2 * DIM];
    const int t = threadIdx.x;
    const int w = t >> 6, lane = t & 63;
    const int quad = lane >> 4, m = lane & 15;
    const int rowbase = blockIdx.x * 128 + w * 32;

    if (TR) {
        if (t < DIM) {
            float a, c;
            bn_coef(stat, gamma, beta, t, a, c);
            tatc[t] = a; tatc[DIM + t] = c;
        }
        __syncthreads();
    }

    bf16x8 a[2][4];
#pragma unroll
    for (int rt = 0; rt < 2; ++rt) {
        int row = rowbase + rt * 16 + m;
        if (row > NN - 1) row = NN - 1;
        const unsigned short* xr = X + (size_t)row * DIM + quad * 8;
#pragma unroll
        for (int ks = 0; ks < 4; ++ks) {
            bf16x8 v = *(const bf16x8*)(xr + ks * 32);
            if (TR) {
                int kk = ks * 32 + quad * 8;
#pragma unroll
                for (int j = 0; j < 8; ++j) {
                    float fv = bfs2f(v[j]);
                    fv = fmaxf(fmaf(fv, tatc[kk + j], tatc[DIM + kk + j]), 0.f);
                    v[j] = (short)f2bf(fv);
                }
            }
            a[rt][ks] = v;
        }
    }

    floatx4 acc[2][8];
#pragma unroll
    for (int rt = 0; rt < 2; ++rt)
#pragma unroll
        for (int ct = 0; ct < 8; ++ct) acc[rt][ct] = (floatx4)0.f;

#pragma unroll
    for (int ct = 0; ct < 8; ++ct) {
        const unsigned short* wr = Wt + (size_t)(ct * 16 + m) * DIM + quad * 8;
#pragma unroll
        for (int ks = 0; ks < 4; ++ks) {
            bf16x8 b = *(const bf16x8*)(wr + ks * 32);
            acc[0][ct] = __builtin_amdgcn_mfma_f32_16x16x32_bf16(a[0][ks], b, acc[0][ct], 0, 0, 0);
            acc[1][ct] = __builtin_amdgcn_mfma_f32_16x16x32_bf16(a[1][ks], b, acc[1][ct], 0, 0, 0);
        }
    }

    // epilogue: bias + bf16 store + masked column stats
#pragma unroll
    for (int ct = 0; ct < 8; ++ct) {
        int col = ct * 16 + m;
        float bv = bias[col];
        float s = 0.f, q = 0.f;
#pragma unroll
        for (int rt = 0; rt < 2; ++rt) {
#pragma unroll
            for (int r = 0; r < 4; ++r) {
                int row = rowbase + rt * 16 + quad * 4 + r;
                float val = acc[rt][ct][r] + bv;
                if (row < NN) {
                    Y[(size_t)row * DIM + col] = (unsigned short)f2bf(val);
                    s += val;
                    q = fmaf(val, val, q);
                }
            }
        }
        s += __shfl_xor(s, 16); s += __shfl_xor(s, 32);
        q += __shfl_xor(q, 16); q += __shfl_xor(q, 32);
        if (quad == 0) { red[w * 256 + col] = s; red[w * 256 + 128 + col] = q; }
    }
    __syncthreads();
    if (t < 256) {
        float tot = red[t] + red[256 + t] + red[512 + t] + red[768 + t];
        unsafeAtomicAdd(&ostat[t], tot);
    }
}

// Per-graph sum pooling (sorted graph_ids), bf16 input, fp32 accumulation.
// 32 nodes/block (3125 blocks). BN fold in-register (TR=1).
template<int TR>
__global__ void pool_nodes(const unsigned* __restrict__ hq, const int* __restrict__ gid,
                           const float* __restrict__ stat, const float* __restrict__ gamma,
                           const float* __restrict__ beta, float* __restrict__ pg) {
    const int lane = threadIdx.x;            // 64 threads, feature pair per lane
    int start = blockIdx.x * 32;
    int end = start + 32;
    if (end > NN) end = NN;
    int f = lane * 2;
    float a0 = 0.f, c0 = 0.f, a1 = 0.f, c1 = 0.f;
    if (TR) {
        bn_coef(stat, gamma, beta, f, a0, c0);
        bn_coef(stat, gamma, beta, f + 1, a1, c1);
    }
    int cur = gid[start];
    float acc0 = 0.f, acc1 = 0.f;
    for (int i = start; i < end; ++i) {
        int g = gid[i];
        if (g != cur) {
            unsafeAtomicAdd(&pg[cur * DIM + f], acc0);
            unsafeAtomicAdd(&pg[cur * DIM + f + 1], acc1);
            acc0 = 0.f; acc1 = 0.f;
            cur = g;
        }
        unsigned u = hq[(size_t)i * 64 + lane];
        float x0 = bf_lo(u), x1 = bf_hi(u);
        if (TR) {
            x0 = fmaxf(fmaf(x0, a0, c0), 0.f);
            x1 = fmaxf(fmaf(x1, a1, c1), 0.f);
        }
        acc0 += x0; acc1 += x1;
    }
    unsafeAtomicAdd(&pg[cur * DIM + f], acc0);
    unsafeAtomicAdd(&pg[cur * DIM + f + 1], acc1);
}

__global__ void final_score(const float* __restrict__ pg, const float* __restrict__ predW,
                            const float* __restrict__ predb, float* __restrict__ out) {
    int g = blockIdx.x;
    int o = threadIdx.x;
    float acc = 0.f;
    for (int l = 0; l <= NL; ++l) {
        acc += predb[l * OUTD + o];
        const float* pgr = pg + ((size_t)l * NG + g) * DIM;
        const float* w = predW + (size_t)l * DIM * OUTD;
#pragma unroll 8
        for (int k = 0; k < DIM; ++k)
            acc = fmaf(pgr[k], w[k * OUTD + o], acc);
    }
    out[g * OUTD + o] = acc;
}

extern "C" void kernel_launch(void* const* d_in, const int* in_sizes, int n_in,
                              void* d_out, int out_size, void* d_ws, size_t ws_size,
                              hipStream_t stream) {
    const float* x     = (const float*)d_in[0];
    const int*   esrc  = (const int*)d_in[1];
    const int*   edst  = (const int*)d_in[2];
    const int*   gid   = (const int*)d_in[3];
    const float* eps   = (const float*)d_in[4];
    const float* W1    = (const float*)d_in[5];
    const float* b1    = (const float*)d_in[6];
    const float* g1    = (const float*)d_in[7];
    const float* be1   = (const float*)d_in[8];
    const float* W2    = (const float*)d_in[9];
    const float* b2    = (const float*)d_in[10];
    const float* g2    = (const float*)d_in[11];
    const float* be2   = (const float*)d_in[12];
    const float* predW = (const float*)d_in[13];
    const float* predb = (const float*)d_in[14];
    float* out = (float*)d_out;

    // ws layout (~85 MB): 3 bf16 node buffers + Wt + [PG|STATS|DEG one-memset
    // region] + CSR arrays
    unsigned short* XB = (unsigned short*)d_ws;
    unsigned short* A  = XB + (size_t)NN * DIM;
    unsigned short* B  = A + (size_t)NN * DIM;
    unsigned short* WT = B + (size_t)NN * DIM;
    float* PG    = (float*)(WT + 8 * DIM * DIM);
    float* STATS = PG + 5 * NG * DIM;          // 4 layers x 512: [S1|SQ1|S2|SQ2]
    int* DEG  = (int*)(STATS + NL * 512);
    int* LOC  = DEG + NN;
    int* OFFS = LOC + NN;
    int* CUR  = OFFS + NN;
    int* BS   = CUR + NN;
    int* PERM = BS + 128;

    // one memset covers PG + all per-layer stats + DEG (contiguous)
    hipMemsetAsync(PG, 0, (5 * NG * DIM + NL * 512) * sizeof(float) + NN * sizeof(int),
                   stream);

    // ---- one-time per call: CSR build, x->bf16, transposed bf16 weights
    const int eBlocks = (NE + 255) / 256;
    hist<<<eBlocks, 256, 0, stream>>>(edst, DEG);
    scan_local<<<NB, 256, 0, stream>>>(DEG, LOC, BS);
    scan_sums<<<1, 128, 0, stream>>>(BS);
    scan_add<<<(NN + 255) / 256, 256, 0, stream>>>(LOC, BS, OFFS, CUR);
    scatter_sliced<<<dim3(NSL, (NE + SL_CH - 1) / SL_CH), 256, 0, stream>>>(esrc, edst,
                                                                            CUR, PERM);
    to_bf16<<<(NN * DIM) / 1024, 256, 0, stream>>>(x, (unsigned*)XB);
    build_wt<<<dim3(8, 8), 256, 0, stream>>>(W1, W2, WT);

    const int poolBlocks = (NN + 31) / 32;
    const int aggBlocks  = (NN + 3) / 4;
    const int gemmBlocks = (NN + 127) / 128;

    const unsigned* h = (const unsigned*)XB;
    for (int l = 0; l < NL; ++l) {
        float* STATL = STATS + l * 512;
        if (l == 0) {
            pool_nodes<0><<<poolBlocks, 64, 0, stream>>>(h, gid, nullptr, nullptr, nullptr, PG);
            csr_agg<0><<<aggBlocks, 256, 0, stream>>>(h, OFFS, PERM, eps, l,
                                                      nullptr, nullptr, nullptr, (unsigned*)B);
        } else {
            const float* prevS = STATS + (l - 1) * 512 + 256;
            const float* gg = g2 + (l - 1) * DIM;
            const float* bb = be2 + (l - 1) * DIM;
            pool_nodes<1><<<poolBlocks, 64, 0, stream>>>(h, gid, prevS, gg, bb,
                                                         PG + l * NG * DIM);
            csr_agg<1><<<aggBlocks, 256, 0, stream>>>(h, OFFS, PERM, eps, l,
                                                      prevS, gg, bb, (unsigned*)B);
        }
        gemm_mfma<0><<<gemmBlocks, 256, 0, stream>>>(B, WT + (size_t)(2 * l) * DIM * DIM,
                                                     b1 + l * DIM, nullptr, nullptr, nullptr,
                                                     B, STATL);
        gemm_mfma<1><<<gemmBlocks, 256, 0, stream>>>(B, WT + (size_t)(2 * l + 1) * DIM * DIM,
                                                     b2 + l * DIM, STATL, g1 + l * DIM,
                                                     be1 + l * DIM, A, STATL + 256);
        h = (const unsigned*)A;
    }
    pool_nodes<1><<<poolBlocks, 64, 0, stream>>>(h, gid, STATS + (NL - 1) * 512 + 256,
                                                 g2 + (NL - 1) * DIM, be2 + (NL - 1) * DIM,
                                                 PG + NL * NG * DIM);
    final_score<<<NG, OUTD, 0, stream>>>(PG, predW, predb, out);
}